// Round 1
// baseline (1796.151 us; speedup 1.0000x reference)
//
#include <hip/hip_runtime.h>

#define DD 1024
#define LL 4
#define HH 8
#define BB 2
#define TT 2048
#define VV 32000
#define SCALE_QK 0.08838834764831845f

typedef __bf16 bf16x8 __attribute__((ext_vector_type(8)));
typedef __bf16 bf16x4 __attribute__((ext_vector_type(4)));
typedef float  f32x4  __attribute__((ext_vector_type(4)));

__device__ __forceinline__ void gload_lds16(const void* g, void* l) {
  __builtin_amdgcn_global_load_lds((const __attribute__((address_space(1))) void*)g,
                                   (__attribute__((address_space(3))) void*)l, 16, 0, 0);
}

// ---------------- NT GEMM: C[M,N] = A[M,K] * Bt[N,K]^T (+epilogue) ----------------
// MODE 0: C bf16 plain
// MODE 1: C f32 plain
// MODE 2: C f32 = acc + bias[n] + res[row,n]
// MODE 3: C bf16 = leakyrelu(acc + bias[n])
// MODE 4: C f32 = acc + bias[n]
template<int MODE>
__global__ __launch_bounds__(256)
void gemm_nt(const __bf16* __restrict__ A, long ldA, long aSB, long aSH,
             const __bf16* __restrict__ Bt, long ldB, long bSB, long bSH,
             void* __restrict__ Cv, long ldC, long cSB, long cSH,
             const float* __restrict__ bias,
             const float* __restrict__ res, long ldR,
             int K)
{
  const int zb = blockIdx.z >> 3, zh = blockIdx.z & 7;
  A  += (size_t)zb * aSB + (size_t)zh * aSH;
  Bt += (size_t)zb * bSB + (size_t)zh * bSH;
  const size_t cOff = (size_t)zb * cSB + (size_t)zh * cSH;

  __shared__ __attribute__((aligned(16))) __bf16 As[128 * 32];
  __shared__ __attribute__((aligned(16))) __bf16 Bs[128 * 32];

  const int tid = threadIdx.x;
  const int wv = tid >> 6, ln = tid & 63;
  const int m0 = blockIdx.y * 128, n0 = blockIdx.x * 128;
  const int wr = (wv >> 1) * 64, wc = (wv & 1) * 64;
  const int lr = ln & 15, lk = (ln >> 4) * 8;
  const int srow = wv * 16 + (ln >> 2);   // staging row within 64-row half
  const int skel = (ln & 3) * 8;          // staging k element offset

  f32x4 acc[4][4] = {};

  for (int k0 = 0; k0 < K; k0 += 32) {
    __syncthreads();
    gload_lds16(A  + (size_t)(m0      + srow) * ldA + k0 + skel, (char*)As +        wv * 1024 + ln * 16);
    gload_lds16(A  + (size_t)(m0 + 64 + srow) * ldA + k0 + skel, (char*)As + 4096 + wv * 1024 + ln * 16);
    gload_lds16(Bt + (size_t)(n0      + srow) * ldB + k0 + skel, (char*)Bs +        wv * 1024 + ln * 16);
    gload_lds16(Bt + (size_t)(n0 + 64 + srow) * ldB + k0 + skel, (char*)Bs + 4096 + wv * 1024 + ln * 16);
    __syncthreads();
    bf16x8 af[4], bfr[4];
#pragma unroll
    for (int i = 0; i < 4; i++) af[i]  = *(const bf16x8*)&As[(wr + i * 16 + lr) * 32 + lk];
#pragma unroll
    for (int i = 0; i < 4; i++) bfr[i] = *(const bf16x8*)&Bs[(wc + i * 16 + lr) * 32 + lk];
#pragma unroll
    for (int i = 0; i < 4; i++)
#pragma unroll
      for (int j = 0; j < 4; j++)
        acc[i][j] = __builtin_amdgcn_mfma_f32_16x16x32_bf16(af[i], bfr[j], acc[i][j], 0, 0, 0);
  }

  const int rb = m0 + wr + (ln >> 4) * 4;
  const int cb = n0 + wc + (ln & 15);
#pragma unroll
  for (int i = 0; i < 4; i++)
#pragma unroll
    for (int j = 0; j < 4; j++) {
      const int col = cb + j * 16;
#pragma unroll
      for (int r = 0; r < 4; r++) {
        const int row = rb + i * 16 + r;
        float v = acc[i][j][r];
        const size_t ci = cOff + (size_t)row * ldC + col;
        if (MODE == 0)      ((__bf16*)Cv)[ci] = (__bf16)v;
        else if (MODE == 1) ((float*)Cv)[ci] = v;
        else if (MODE == 2) ((float*)Cv)[ci] = v + bias[col] + res[(size_t)row * ldR + col];
        else if (MODE == 3) { v += bias[col]; ((__bf16*)Cv)[ci] = (__bf16)(v >= 0.f ? v : 0.01f * v); }
        else                ((float*)Cv)[ci] = v + bias[col];
      }
    }
}

// ---------------- weight transpose + fp32->bf16: Wt[n*K+k] = W[k*N+n] ----------------
__global__ void wtrans(const float* __restrict__ W, __bf16* __restrict__ Wt, int K, int N)
{
  const size_t zo = (size_t)blockIdx.z * K * N;
  __shared__ float t[32][33];
  const int n0 = blockIdx.x * 32, k0 = blockIdx.y * 32;
  const int tx = threadIdx.x, ty = threadIdx.y;
#pragma unroll
  for (int r = 0; r < 4; r++)
    t[ty + r * 8][tx] = W[zo + (size_t)(k0 + ty + r * 8) * N + n0 + tx];
  __syncthreads();
#pragma unroll
  for (int r = 0; r < 4; r++)
    Wt[zo + (size_t)(n0 + ty + r * 8) * K + k0 + tx] = (__bf16)t[tx][ty + r * 8];
}

// ---------------- V transpose per (b,h): Vt[z][n][i] = qkv[b, i*H+h, 2D+n] ----------------
__global__ void vtrans(const __bf16* __restrict__ qkv, __bf16* __restrict__ Vt)
{
  const int z = blockIdx.z, bb = z >> 3, hh = z & 7;
  const __bf16* src = qkv + ((size_t)bb * TT + hh) * (3 * DD) + 2 * DD;
  __bf16* dst = Vt + (size_t)z * DD * 256;
  __shared__ __bf16 t[32][33];
  const int n0 = blockIdx.x * 32, i0 = blockIdx.y * 32;
  const int tx = threadIdx.x, ty = threadIdx.y;
#pragma unroll
  for (int r = 0; r < 4; r++)
    t[ty + r * 8][tx] = src[(size_t)(i0 + ty + r * 8) * (HH * 3 * DD) + n0 + tx];
  __syncthreads();
#pragma unroll
  for (int r = 0; r < 4; r++)
    dst[(size_t)(n0 + ty + r * 8) * 256 + i0 + tx] = t[tx][ty + r * 8];
}

// ---------------- embedding gather ----------------
__global__ void embed_k(const int* __restrict__ x, const float* __restrict__ emb, float* __restrict__ h)
{
  const int row = blockIdx.x;
  const int tok = x[row];
  ((float4*)(h + (size_t)row * DD))[threadIdx.x] = ((const float4*)(emb + (size_t)tok * DD))[threadIdx.x];
}

// ---------------- layernorm row -> bf16 ----------------
__global__ void ln_rows(const float* __restrict__ x, const float* __restrict__ g,
                        const float* __restrict__ b, __bf16* __restrict__ y)
{
  const int row = blockIdx.x, t = threadIdx.x;
  const int wv = t >> 6, ln = t & 63;
  const float4 v = ((const float4*)(x + (size_t)row * DD))[t];
  float s  = v.x + v.y + v.z + v.w;
  float ss = v.x * v.x + v.y * v.y + v.z * v.z + v.w * v.w;
#pragma unroll
  for (int o = 32; o; o >>= 1) { s += __shfl_xor(s, o); ss += __shfl_xor(ss, o); }
  __shared__ float rs_[4], rss_[4];
  if (!ln) { rs_[wv] = s; rss_[wv] = ss; }
  __syncthreads();
  s  = rs_[0] + rs_[1] + rs_[2] + rs_[3];
  ss = rss_[0] + rss_[1] + rss_[2] + rss_[3];
  const float mu  = s * (1.0f / DD);
  const float var = ss * (1.0f / DD) - mu * mu;
  const float r   = rsqrtf(var + 1e-5f);
  const float4 gv = ((const float4*)g)[t];
  const float4 bv = ((const float4*)b)[t];
  bf16x4 o = { (__bf16)((v.x - mu) * r * gv.x + bv.x),
               (__bf16)((v.y - mu) * r * gv.y + bv.y),
               (__bf16)((v.z - mu) * r * gv.z + bv.z),
               (__bf16)((v.w - mu) * r * gv.w + bv.w) };
  ((bf16x4*)(y + (size_t)row * DD))[t] = o;
}

// ---------------- softmax over 256-wide rows (with QK scale) -> bf16 ----------------
__global__ void softmax256(const float* __restrict__ S, __bf16* __restrict__ P)
{
  const int row = blockIdx.x, t = threadIdx.x;
  const int wv = t >> 6, ln = t & 63;
  const float v = S[(size_t)row * 256 + t] * SCALE_QK;
  float m = v;
#pragma unroll
  for (int o = 32; o; o >>= 1) m = fmaxf(m, __shfl_xor(m, o));
  __shared__ float red[8];
  if (!ln) red[wv] = m;
  __syncthreads();
  m = fmaxf(fmaxf(red[0], red[1]), fmaxf(red[2], red[3]));
  const float e = __expf(v - m);
  float s = e;
#pragma unroll
  for (int o = 32; o; o >>= 1) s += __shfl_xor(s, o);
  if (!ln) red[4 + wv] = s;
  __syncthreads();
  s = red[4] + red[5] + red[6] + red[7];
  P[(size_t)row * 256 + t] = (__bf16)(e / s);
}

// ---------------- fp32 -> bf16 convert (8 elems/thread) ----------------
__global__ void f2bf(const float* __restrict__ h, __bf16* __restrict__ y)
{
  const size_t i = (size_t)blockIdx.x * 256 + threadIdx.x;
  const float4 a = ((const float4*)h)[2 * i];
  const float4 b = ((const float4*)h)[2 * i + 1];
  bf16x8 o = { (__bf16)a.x, (__bf16)a.y, (__bf16)a.z, (__bf16)a.w,
               (__bf16)b.x, (__bf16)b.y, (__bf16)b.z, (__bf16)b.w };
  ((bf16x8*)y)[i] = o;
}

template<int MODE>
static void G(const __bf16* A, long ldA, long aSB, long aSH,
              const __bf16* Bt, long ldB, long bSB, long bSH,
              void* C, long ldC, long cSB, long cSH,
              const float* bias, const float* res, long ldR,
              int M, int N, int K, int Z, hipStream_t s)
{
  gemm_nt<MODE><<<dim3(N / 128, M / 128, Z), 256, 0, s>>>(
      A, ldA, aSB, aSH, Bt, ldB, bSB, bSH, C, ldC, cSB, cSH, bias, res, ldR, K);
}

extern "C" void kernel_launch(void* const* d_in, const int* in_sizes, int n_in,
                              void* d_out, int out_size, void* d_ws, size_t ws_size,
                              hipStream_t stream)
{
  const int*   x       = (const int*)  d_in[0];
  const float* emb     = (const float*)d_in[1];
  const float* ln1_g   = (const float*)d_in[2];
  const float* ln1_b   = (const float*)d_in[3];
  const float* wqkv    = (const float*)d_in[4];
  const float* wout_w  = (const float*)d_in[5];
  const float* wout_b  = (const float*)d_in[6];
  const float* ln2_g   = (const float*)d_in[7];
  const float* ln2_b   = (const float*)d_in[8];
  const float* ff1_w   = (const float*)d_in[9];
  const float* ff1_b   = (const float*)d_in[10];
  const float* ff2_w   = (const float*)d_in[11];
  const float* ff2_b   = (const float*)d_in[12];
  const float* logit_w = (const float*)d_in[13];
  const float* logit_b = (const float*)d_in[14];
  float* out = (float*)d_out;

  char* w = (char*)d_ws;
  size_t off = 0;
  auto take = [&](size_t bytes) { void* p = w + off; off += (bytes + 255) & ~(size_t)255; return p; };
  __bf16* wqkvT = (__bf16*)take((size_t)LL * 3 * DD * DD * 2);
  __bf16* woutT = (__bf16*)take((size_t)LL * DD * DD * 2);
  __bf16* ff1T  = (__bf16*)take((size_t)LL * 4 * DD * DD * 2);
  __bf16* ff2T  = (__bf16*)take((size_t)LL * DD * 4 * DD * 2);
  __bf16* logT  = (__bf16*)take((size_t)VV * DD * 2);
  float*  h     = (float*) take((size_t)BB * TT * DD * 4);
  __bf16* ybf   = (__bf16*)take((size_t)BB * TT * DD * 2);
  __bf16* qkvbf = (__bf16*)take((size_t)BB * TT * 3 * DD * 2);
  float*  Smat  = (float*) take((size_t)BB * HH * 256 * 256 * 4);
  __bf16* Pbf   = (__bf16*)take((size_t)BB * HH * 256 * 256 * 2);
  __bf16* Vt    = (__bf16*)take((size_t)BB * HH * DD * 256 * 2);
  __bf16* Obf   = (__bf16*)take((size_t)BB * TT * DD * 2);
  __bf16* midbf = (__bf16*)take((size_t)BB * TT * 4 * DD * 2);
  if (ws_size < off) return;  // workspace too small: leave output untouched (visible fail)

  const dim3 tb(32, 8);
  // weight transpose+convert pre-pass
  wtrans<<<dim3(3 * DD / 32, DD / 32, LL), tb, 0, stream>>>(wqkv,   wqkvT, DD, 3 * DD);
  wtrans<<<dim3(DD / 32,     DD / 32, LL), tb, 0, stream>>>(wout_w, woutT, DD, DD);
  wtrans<<<dim3(4 * DD / 32, DD / 32, LL), tb, 0, stream>>>(ff1_w,  ff1T,  DD, 4 * DD);
  wtrans<<<dim3(DD / 32, 4 * DD / 32, LL), tb, 0, stream>>>(ff2_w,  ff2T,  4 * DD, DD);
  wtrans<<<dim3(VV / 32,     DD / 32, 1),  tb, 0, stream>>>(logit_w, logT, DD, VV);

  const int M = BB * TT;
  embed_k<<<M, 256, 0, stream>>>(x, emb, h);

  for (int l = 0; l < LL; l++) {
    ln_rows<<<M, 256, 0, stream>>>(h, ln1_g + l * DD, ln1_b + l * DD, ybf);
    // qkv = y @ wqkv
    G<0>(ybf, DD, 0, 0, wqkvT + (size_t)l * 3 * DD * DD, DD, 0, 0,
         qkvbf, 3 * DD, 0, 0, nullptr, nullptr, 0, M, 3 * DD, DD, 1, stream);
    // S = Q @ K^T  (per b,h; strided rows within qkv)
    G<1>(qkvbf, HH * 3 * DD, (long)TT * 3 * DD, 3 * DD,
         qkvbf + DD, HH * 3 * DD, (long)TT * 3 * DD, 3 * DD,
         Smat, 256, (long)HH * 256 * 256, 256 * 256,
         nullptr, nullptr, 0, 256, 256, DD, BB * HH, stream);
    softmax256<<<BB * HH * 256, 256, 0, stream>>>(Smat, Pbf);
    vtrans<<<dim3(DD / 32, 256 / 32, BB * HH), tb, 0, stream>>>(qkvbf, Vt);
    // O = P @ V
    G<0>(Pbf, 256, (long)HH * 256 * 256, 256 * 256,
         Vt, 256, (long)HH * DD * 256, (long)DD * 256,
         Obf, HH * DD, (long)TT * DD, DD,
         nullptr, nullptr, 0, 256, DD, 256, BB * HH, stream);
    // h += O @ wout + b
    G<2>(Obf, DD, 0, 0, woutT + (size_t)l * DD * DD, DD, 0, 0,
         h, DD, 0, 0, wout_b + l * DD, h, DD, M, DD, DD, 1, stream);
    ln_rows<<<M, 256, 0, stream>>>(h, ln2_g + l * DD, ln2_b + l * DD, ybf);
    // mid = lrelu(y @ ff1 + b1)
    G<3>(ybf, DD, 0, 0, ff1T + (size_t)l * 4 * DD * DD, DD, 0, 0,
         midbf, 4 * DD, 0, 0, ff1_b + (size_t)l * 4 * DD, nullptr, 0, M, 4 * DD, DD, 1, stream);
    // h += mid @ ff2 + b2
    G<2>(midbf, 4 * DD, 0, 0, ff2T + (size_t)l * DD * 4 * DD, 4 * DD, 0, 0,
         h, DD, 0, 0, ff2_b + l * DD, h, DD, M, DD, 4 * DD, 1, stream);
  }

  f2bf<<<(M * DD / 8) / 256, 256, 0, stream>>>(h, ybf);
  // logits = h @ logit_w + logit_b
  G<4>(ybf, DD, 0, 0, logT, DD, 0, 0,
       out, VV, 0, 0, logit_b, nullptr, 0, M, VV, DD, 1, stream);
}

// Round 2
// 1620.277 us; speedup vs baseline: 1.1085x; 1.1085x over previous
//
#include <hip/hip_runtime.h>

#define DD 1024
#define LL 4
#define HH 8
#define BB 2
#define TT 2048
#define VV 32000
#define SCALE_QK 0.08838834764831845f

typedef __bf16 bf16x8 __attribute__((ext_vector_type(8)));
typedef __bf16 bf16x4 __attribute__((ext_vector_type(4)));
typedef float  f32x4  __attribute__((ext_vector_type(4)));

__device__ __forceinline__ void gload_lds16(const void* g, void* l) {
  __builtin_amdgcn_global_load_lds((const __attribute__((address_space(1))) void*)g,
                                   (__attribute__((address_space(3))) void*)l, 16, 0, 0);
}

// =====================================================================
// 256x256 8-phase GEMM (T1+T2+T3+T4+T5): C[M,N] = A[M,K] * Bt[N,K]^T
// MODE 0: C bf16 plain ; MODE 3: C bf16 = leakyrelu(acc+bias) ; MODE 4: C f32 = acc+bias
// LDS 128 KiB dynamic: A ring4 x 16KB at [0,64K), B ring4 at [64K,128K)
// unit u = 2*t + ksub, slot = u & 3.
// Swizzled layout within a unit: 128B line = row-pair; granule g in [0,8):
//   content(line,g): u'=g^(line&7); row=2*line+(u'>>2); kslot=u'&3 (8 bf16 each)
// =====================================================================
template<int MODE>
__global__ __launch_bounds__(512, 2)
void gemm256(const __bf16* __restrict__ A, long ldA,
             const __bf16* __restrict__ Bt, long ldB,
             void* __restrict__ Cv, long ldC,
             const float* __restrict__ bias,
             int K, int nby)
{
  extern __shared__ __attribute__((aligned(16))) char smem[];

  // T1: bijective XCD swizzle, column-major inner (consecutive ids share B-panel)
  const int nwg = gridDim.x;
  const int o = blockIdx.x;
  const int q8 = nwg >> 3, r8 = nwg & 7;
  const int xcd = o & 7, idx = o >> 3;
  const int swz = (xcd < r8 ? xcd * (q8 + 1) : r8 * (q8 + 1) + (xcd - r8) * q8) + idx;
  const int bx = swz / nby, by = swz - bx * nby;
  const int m0 = by * 256, n0 = bx * 256;

  const int tid = threadIdx.x;
  const int wv = tid >> 6, ln = tid & 63;
  const int wm = wv >> 2, wn = wv & 3;

  // staging: per-lane pre-swizzled global source (rule 21)
  const int u = (ln & 7) ^ (ln >> 3);
  const int dR = u >> 2;
  const int dK = (u & 3) << 3;
  const int row0 = (wv * 16 + (ln >> 3)) * 2 + dR;
  const __bf16* aS0 = A  + (size_t)(m0 + row0) * ldA + dK;
  const __bf16* aS1 = A  + (size_t)(m0 + row0 + 16) * ldA + dK;
  const __bf16* bS0 = Bt + (size_t)(n0 + row0) * ldB + dK;
  const __bf16* bS1 = Bt + (size_t)(n0 + row0 + 16) * ldB + dK;
  char* const dBase = smem + wv * 2048 + ln * 16;

  // fragment read offsets (conflict-free: 8 lanes per bank-group)
  const int lr = ln & 15;
  const int gfr = ((((ln & 1) << 2) | ((ln >> 4) & 3)) ^ ((ln >> 1) & 7)) << 4;
  const int aRd = (wm * 64 + (lr >> 1)) * 128 + gfr;
  const int bRd = 65536 + (wn * 32 + (lr >> 1)) * 128 + gfr;

  f32x4 acc[8][4] = {};
  bf16x8 b[4];
  const int NT = K >> 6;

#define STG_A(tt, ks) { const int sl = ((2*(tt)+(ks)) & 3) * 16384; \
    gload_lds16(aS0 + (tt)*64 + (ks)*32, dBase + sl); \
    gload_lds16(aS1 + (tt)*64 + (ks)*32, dBase + sl + 1024); }
#define STG_B(tt, ks) { const int sl = ((2*(tt)+(ks)) & 3) * 16384 + 65536; \
    gload_lds16(bS0 + (tt)*64 + (ks)*32, dBase + sl); \
    gload_lds16(bS1 + (tt)*64 + (ks)*32, dBase + sl + 1024); }
#define BAR() { __builtin_amdgcn_sched_barrier(0); __builtin_amdgcn_s_barrier(); __builtin_amdgcn_sched_barrier(0); }
#define MFMA_Q(MH) \
    __builtin_amdgcn_s_setprio(1); \
    _Pragma("unroll") \
    for (int i = 0; i < 4; i++) \
      _Pragma("unroll") \
      for (int j = 0; j < 4; j++) \
        acc[(MH)*4+i][j] = __builtin_amdgcn_mfma_f32_16x16x32_bf16(a[i], b[j], acc[(MH)*4+i][j], 0,0,0); \
    __builtin_amdgcn_s_setprio(0);

  // prologue: units 0,1 (tile0) + unit 2 (tile1,k0); allow unit2's 4 loads in flight
  STG_A(0, 0); STG_B(0, 0); STG_A(0, 1); STG_B(0, 1);
  if (NT > 1) {
    STG_A(1, 0); STG_B(1, 0);
    asm volatile("s_waitcnt vmcnt(4)" ::: "memory");
  } else {
    asm volatile("s_waitcnt vmcnt(0)" ::: "memory");
  }
  BAR();

  for (int t = 0; t < NT; ++t) {
    const char* uA0 = smem + ((2 * t) & 3) * 16384;
    const char* uA1 = smem + ((2 * t + 1) & 3) * 16384;
    bf16x8 a[4];
    // ---- p0: m-half0, ksub0 ----
#pragma unroll
    for (int i = 0; i < 4; i++) a[i] = *(const bf16x8*)(uA0 + aRd + i * 1024);
#pragma unroll
    for (int j = 0; j < 4; j++) b[j] = *(const bf16x8*)(uA0 + bRd + j * 1024);
    if (t + 1 < NT) STG_A(t + 1, 1);
    BAR();
    MFMA_Q(0);
    BAR();
    // ---- p1: m-half1, ksub0 (B regs reused) ----
#pragma unroll
    for (int i = 0; i < 4; i++) a[i] = *(const bf16x8*)(uA0 + aRd + (4 + i) * 1024);
    if (t + 1 < NT) STG_B(t + 1, 1);
    BAR();
    MFMA_Q(1);
    BAR();
    // ---- p2: m-half0, ksub1 ----
#pragma unroll
    for (int i = 0; i < 4; i++) a[i] = *(const bf16x8*)(uA1 + aRd + i * 1024);
#pragma unroll
    for (int j = 0; j < 4; j++) b[j] = *(const bf16x8*)(uA1 + bRd + j * 1024);
    if (t + 2 < NT) STG_A(t + 2, 0);
    BAR();
    MFMA_Q(0);
    BAR();
    // ---- p3: m-half1, ksub1 ----
#pragma unroll
    for (int i = 0; i < 4; i++) a[i] = *(const bf16x8*)(uA1 + aRd + (4 + i) * 1024);
    if (t + 2 < NT) STG_B(t + 2, 0);
    BAR();
    MFMA_Q(1);
    __builtin_amdgcn_sched_barrier(0);
    // boundary: ensure tile t+1's 4 units landed; allow unit-(2t+4)'s 4 loads in flight
    if (t + 2 < NT)      { asm volatile("s_waitcnt vmcnt(4)" ::: "memory"); }
    else if (t + 1 < NT) { asm volatile("s_waitcnt vmcnt(0)" ::: "memory"); }
    BAR();
  }
#undef STG_A
#undef STG_B
#undef BAR
#undef MFMA_Q

  // epilogue
  const int rb = m0 + wm * 128 + (ln >> 4) * 4;
  const int cb = n0 + wn * 64 + (ln & 15);
#pragma unroll
  for (int i = 0; i < 8; i++)
#pragma unroll
    for (int j = 0; j < 4; j++) {
      const int col = cb + j * 16;
#pragma unroll
      for (int r = 0; r < 4; r++) {
        const int row = rb + i * 16 + r;
        float v = acc[i][j][r];
        const size_t ci = (size_t)row * ldC + col;
        if (MODE == 0)      ((__bf16*)Cv)[ci] = (__bf16)v;
        else if (MODE == 3) { v += bias[col]; ((__bf16*)Cv)[ci] = (__bf16)(v >= 0.f ? v : 0.01f * v); }
        else if (MODE == 4) ((float*)Cv)[ci] = v + bias[col];
      }
    }
}

// ---------------- legacy 128x128 NT GEMM (attention / N=1024 shapes) ----------------
// MODE 0: C bf16 ; MODE 1: C f32 ; MODE 2: C f32 = acc+bias+res
template<int MODE>
__global__ __launch_bounds__(256)
void gemm_nt(const __bf16* __restrict__ A, long ldA, long aSB, long aSH,
             const __bf16* __restrict__ Bt, long ldB, long bSB, long bSH,
             void* __restrict__ Cv, long ldC, long cSB, long cSH,
             const float* __restrict__ bias,
             const float* __restrict__ res, long ldR,
             int K)
{
  const int zb = blockIdx.z >> 3, zh = blockIdx.z & 7;
  A  += (size_t)zb * aSB + (size_t)zh * aSH;
  Bt += (size_t)zb * bSB + (size_t)zh * bSH;
  const size_t cOff = (size_t)zb * cSB + (size_t)zh * cSH;

  __shared__ __attribute__((aligned(16))) __bf16 As[128 * 32];
  __shared__ __attribute__((aligned(16))) __bf16 Bs[128 * 32];

  const int tid = threadIdx.x;
  const int wv = tid >> 6, ln = tid & 63;
  const int m0 = blockIdx.y * 128, n0 = blockIdx.x * 128;
  const int wr = (wv >> 1) * 64, wc = (wv & 1) * 64;
  const int lr = ln & 15, lk = (ln >> 4) * 8;
  const int srow = wv * 16 + (ln >> 2);
  const int skel = (ln & 3) * 8;

  f32x4 acc[4][4] = {};

  for (int k0 = 0; k0 < K; k0 += 32) {
    __syncthreads();
    gload_lds16(A  + (size_t)(m0      + srow) * ldA + k0 + skel, (char*)As +        wv * 1024 + ln * 16);
    gload_lds16(A  + (size_t)(m0 + 64 + srow) * ldA + k0 + skel, (char*)As + 4096 + wv * 1024 + ln * 16);
    gload_lds16(Bt + (size_t)(n0      + srow) * ldB + k0 + skel, (char*)Bs +        wv * 1024 + ln * 16);
    gload_lds16(Bt + (size_t)(n0 + 64 + srow) * ldB + k0 + skel, (char*)Bs + 4096 + wv * 1024 + ln * 16);
    __syncthreads();
    bf16x8 af[4], bfr[4];
#pragma unroll
    for (int i = 0; i < 4; i++) af[i]  = *(const bf16x8*)&As[(wr + i * 16 + lr) * 32 + lk];
#pragma unroll
    for (int i = 0; i < 4; i++) bfr[i] = *(const bf16x8*)&Bs[(wc + i * 16 + lr) * 32 + lk];
#pragma unroll
    for (int i = 0; i < 4; i++)
#pragma unroll
      for (int j = 0; j < 4; j++)
        acc[i][j] = __builtin_amdgcn_mfma_f32_16x16x32_bf16(af[i], bfr[j], acc[i][j], 0, 0, 0);
  }

  const int rb = m0 + wr + (ln >> 4) * 4;
  const int cb = n0 + wc + (ln & 15);
#pragma unroll
  for (int i = 0; i < 4; i++)
#pragma unroll
    for (int j = 0; j < 4; j++) {
      const int col = cb + j * 16;
#pragma unroll
      for (int r = 0; r < 4; r++) {
        const int row = rb + i * 16 + r;
        float v = acc[i][j][r];
        const size_t ci = cOff + (size_t)row * ldC + col;
        if (MODE == 0)      ((__bf16*)Cv)[ci] = (__bf16)v;
        else if (MODE == 1) ((float*)Cv)[ci] = v;
        else if (MODE == 2) ((float*)Cv)[ci] = v + bias[col] + res[(size_t)row * ldR + col];
      }
    }
}

// ---------------- weight transpose + fp32->bf16 ----------------
__global__ void wtrans(const float* __restrict__ W, __bf16* __restrict__ Wt, int K, int N)
{
  const size_t zo = (size_t)blockIdx.z * K * N;
  __shared__ float t[32][33];
  const int n0 = blockIdx.x * 32, k0 = blockIdx.y * 32;
  const int tx = threadIdx.x, ty = threadIdx.y;
#pragma unroll
  for (int r = 0; r < 4; r++)
    t[ty + r * 8][tx] = W[zo + (size_t)(k0 + ty + r * 8) * N + n0 + tx];
  __syncthreads();
#pragma unroll
  for (int r = 0; r < 4; r++)
    Wt[zo + (size_t)(n0 + ty + r * 8) * K + k0 + tx] = (__bf16)t[tx][ty + r * 8];
}

// ---------------- V transpose per (b,h) ----------------
__global__ void vtrans(const __bf16* __restrict__ qkv, __bf16* __restrict__ Vt)
{
  const int z = blockIdx.z, bb = z >> 3, hh = z & 7;
  const __bf16* src = qkv + ((size_t)bb * TT + hh) * (3 * DD) + 2 * DD;
  __bf16* dst = Vt + (size_t)z * DD * 256;
  __shared__ __bf16 t[32][33];
  const int n0 = blockIdx.x * 32, i0 = blockIdx.y * 32;
  const int tx = threadIdx.x, ty = threadIdx.y;
#pragma unroll
  for (int r = 0; r < 4; r++)
    t[ty + r * 8][tx] = src[(size_t)(i0 + ty + r * 8) * (HH * 3 * DD) + n0 + tx];
  __syncthreads();
#pragma unroll
  for (int r = 0; r < 4; r++)
    dst[(size_t)(n0 + ty + r * 8) * 256 + i0 + tx] = t[tx][ty + r * 8];
}

// ---------------- embedding gather ----------------
__global__ void embed_k(const int* __restrict__ x, const float* __restrict__ emb, float* __restrict__ h)
{
  const int row = blockIdx.x;
  const int tok = x[row];
  ((float4*)(h + (size_t)row * DD))[threadIdx.x] = ((const float4*)(emb + (size_t)tok * DD))[threadIdx.x];
}

// ---------------- layernorm row -> bf16 ----------------
__global__ void ln_rows(const float* __restrict__ x, const float* __restrict__ g,
                        const float* __restrict__ b, __bf16* __restrict__ y)
{
  const int row = blockIdx.x, t = threadIdx.x;
  const int wv = t >> 6, ln = t & 63;
  const float4 v = ((const float4*)(x + (size_t)row * DD))[t];
  float s  = v.x + v.y + v.z + v.w;
  float ss = v.x * v.x + v.y * v.y + v.z * v.z + v.w * v.w;
#pragma unroll
  for (int o = 32; o; o >>= 1) { s += __shfl_xor(s, o); ss += __shfl_xor(ss, o); }
  __shared__ float rs_[4], rss_[4];
  if (!ln) { rs_[wv] = s; rss_[wv] = ss; }
  __syncthreads();
  s  = rs_[0] + rs_[1] + rs_[2] + rs_[3];
  ss = rss_[0] + rss_[1] + rss_[2] + rss_[3];
  const float mu  = s * (1.0f / DD);
  const float var = ss * (1.0f / DD) - mu * mu;
  const float r   = rsqrtf(var + 1e-5f);
  const float4 gv = ((const float4*)g)[t];
  const float4 bv = ((const float4*)b)[t];
  bf16x4 o = { (__bf16)((v.x - mu) * r * gv.x + bv.x),
               (__bf16)((v.y - mu) * r * gv.y + bv.y),
               (__bf16)((v.z - mu) * r * gv.z + bv.z),
               (__bf16)((v.w - mu) * r * gv.w + bv.w) };
  ((bf16x4*)(y + (size_t)row * DD))[t] = o;
}

// ---------------- softmax over 256-wide rows -> bf16 ----------------
__global__ void softmax256(const float* __restrict__ S, __bf16* __restrict__ P)
{
  const int row = blockIdx.x, t = threadIdx.x;
  const int wv = t >> 6, ln = t & 63;
  const float v = S[(size_t)row * 256 + t] * SCALE_QK;
  float m = v;
#pragma unroll
  for (int o = 32; o; o >>= 1) m = fmaxf(m, __shfl_xor(m, o));
  __shared__ float red[8];
  if (!ln) red[wv] = m;
  __syncthreads();
  m = fmaxf(fmaxf(red[0], red[1]), fmaxf(red[2], red[3]));
  const float e = __expf(v - m);
  float s = e;
#pragma unroll
  for (int o = 32; o; o >>= 1) s += __shfl_xor(s, o);
  if (!ln) red[4 + wv] = s;
  __syncthreads();
  s = red[4] + red[5] + red[6] + red[7];
  P[(size_t)row * 256 + t] = (__bf16)(e / s);
}

// ---------------- fp32 -> bf16 convert ----------------
__global__ void f2bf(const float* __restrict__ h, __bf16* __restrict__ y)
{
  const size_t i = (size_t)blockIdx.x * 256 + threadIdx.x;
  const float4 a = ((const float4*)h)[2 * i];
  const float4 b = ((const float4*)h)[2 * i + 1];
  bf16x8 o = { (__bf16)a.x, (__bf16)a.y, (__bf16)a.z, (__bf16)a.w,
               (__bf16)b.x, (__bf16)b.y, (__bf16)b.z, (__bf16)b.w };
  ((bf16x8*)y)[i] = o;
}

template<int MODE>
static void G(const __bf16* A, long ldA, long aSB, long aSH,
              const __bf16* Bt, long ldB, long bSB, long bSH,
              void* C, long ldC, long cSB, long cSH,
              const float* bias, const float* res, long ldR,
              int M, int N, int K, int Z, hipStream_t s)
{
  gemm_nt<MODE><<<dim3(N / 128, M / 128, Z), 256, 0, s>>>(
      A, ldA, aSB, aSH, Bt, ldB, bSB, bSH, C, ldC, cSB, cSH, bias, res, ldR, K);
}

template<int MODE>
static void G256(const __bf16* A, long ldA, const __bf16* Bt, long ldB,
                 void* C, long ldC, const float* bias,
                 int M, int N, int K, hipStream_t s)
{
  hipFuncSetAttribute((const void*)gemm256<MODE>,
                      hipFuncAttributeMaxDynamicSharedMemorySize, 131072);
  const int nby = M / 256, nbx = N / 256;
  gemm256<MODE><<<dim3(nbx * nby), 512, 131072, s>>>(A, ldA, Bt, ldB, C, ldC, bias, K, nby);
}

extern "C" void kernel_launch(void* const* d_in, const int* in_sizes, int n_in,
                              void* d_out, int out_size, void* d_ws, size_t ws_size,
                              hipStream_t stream)
{
  const int*   x       = (const int*)  d_in[0];
  const float* emb     = (const float*)d_in[1];
  const float* ln1_g   = (const float*)d_in[2];
  const float* ln1_b   = (const float*)d_in[3];
  const float* wqkv    = (const float*)d_in[4];
  const float* wout_w  = (const float*)d_in[5];
  const float* wout_b  = (const float*)d_in[6];
  const float* ln2_g   = (const float*)d_in[7];
  const float* ln2_b   = (const float*)d_in[8];
  const float* ff1_w   = (const float*)d_in[9];
  const float* ff1_b   = (const float*)d_in[10];
  const float* ff2_w   = (const float*)d_in[11];
  const float* ff2_b   = (const float*)d_in[12];
  const float* logit_w = (const float*)d_in[13];
  const float* logit_b = (const float*)d_in[14];
  float* out = (float*)d_out;

  char* w = (char*)d_ws;
  size_t off = 0;
  auto take = [&](size_t bytes) { void* p = w + off; off += (bytes + 255) & ~(size_t)255; return p; };
  __bf16* wqkvT = (__bf16*)take((size_t)LL * 3 * DD * DD * 2);
  __bf16* woutT = (__bf16*)take((size_t)LL * DD * DD * 2);
  __bf16* ff1T  = (__bf16*)take((size_t)LL * 4 * DD * DD * 2);
  __bf16* ff2T  = (__bf16*)take((size_t)LL * DD * 4 * DD * 2);
  __bf16* logT  = (__bf16*)take((size_t)VV * DD * 2);
  float*  h     = (float*) take((size_t)BB * TT * DD * 4);
  __bf16* ybf   = (__bf16*)take((size_t)BB * TT * DD * 2);
  __bf16* qkvbf = (__bf16*)take((size_t)BB * TT * 3 * DD * 2);
  float*  Smat  = (float*) take((size_t)BB * HH * 256 * 256 * 4);
  __bf16* Pbf   = (__bf16*)take((size_t)BB * HH * 256 * 256 * 2);
  __bf16* Vt    = (__bf16*)take((size_t)BB * HH * DD * 256 * 2);
  __bf16* Obf   = (__bf16*)take((size_t)BB * TT * DD * 2);
  __bf16* midbf = (__bf16*)take((size_t)BB * TT * 4 * DD * 2);
  if (ws_size < off) return;

  const dim3 tb(32, 8);
  wtrans<<<dim3(3 * DD / 32, DD / 32, LL), tb, 0, stream>>>(wqkv,   wqkvT, DD, 3 * DD);
  wtrans<<<dim3(DD / 32,     DD / 32, LL), tb, 0, stream>>>(wout_w, woutT, DD, DD);
  wtrans<<<dim3(4 * DD / 32, DD / 32, LL), tb, 0, stream>>>(ff1_w,  ff1T,  DD, 4 * DD);
  wtrans<<<dim3(DD / 32, 4 * DD / 32, LL), tb, 0, stream>>>(ff2_w,  ff2T,  4 * DD, DD);
  wtrans<<<dim3(VV / 32,     DD / 32, 1),  tb, 0, stream>>>(logit_w, logT, DD, VV);

  const int M = BB * TT;
  embed_k<<<M, 256, 0, stream>>>(x, emb, h);

  for (int l = 0; l < LL; l++) {
    ln_rows<<<M, 256, 0, stream>>>(h, ln1_g + l * DD, ln1_b + l * DD, ybf);
    // qkv = y @ wqkv  (8-phase)
    G256<0>(ybf, DD, wqkvT + (size_t)l * 3 * DD * DD, DD,
            qkvbf, 3 * DD, nullptr, M, 3 * DD, DD, stream);
    // S = Q @ K^T  (per b,h)
    G<1>(qkvbf, HH * 3 * DD, (long)TT * 3 * DD, 3 * DD,
         qkvbf + DD, HH * 3 * DD, (long)TT * 3 * DD, 3 * DD,
         Smat, 256, (long)HH * 256 * 256, 256 * 256,
         nullptr, nullptr, 0, 256, 256, DD, BB * HH, stream);
    softmax256<<<BB * HH * 256, 256, 0, stream>>>(Smat, Pbf);
    vtrans<<<dim3(DD / 32, 256 / 32, BB * HH), tb, 0, stream>>>(qkvbf, Vt);
    // O = P @ V
    G<0>(Pbf, 256, (long)HH * 256 * 256, 256 * 256,
         Vt, 256, (long)HH * DD * 256, (long)DD * 256,
         Obf, HH * DD, (long)TT * DD, DD,
         nullptr, nullptr, 0, 256, DD, 256, BB * HH, stream);
    // h += O @ wout + b  (N=1024 -> legacy tile)
    G<2>(Obf, DD, 0, 0, woutT + (size_t)l * DD * DD, DD, 0, 0,
         h, DD, 0, 0, wout_b + l * DD, h, DD, M, DD, DD, 1, stream);
    ln_rows<<<M, 256, 0, stream>>>(h, ln2_g + l * DD, ln2_b + l * DD, ybf);
    // mid = lrelu(y @ ff1 + b1)  (8-phase)
    G256<3>(ybf, DD, ff1T + (size_t)l * 4 * DD * DD, DD,
            midbf, 4 * DD, ff1_b + (size_t)l * 4 * DD, M, 4 * DD, DD, stream);
    // h += mid @ ff2 + b2  (N=1024 -> legacy tile)
    G<2>(midbf, 4 * DD, 0, 0, ff2T + (size_t)l * DD * 4 * DD, 4 * DD, 0, 0,
         h, DD, 0, 0, ff2_b + l * DD, h, DD, M, DD, 4 * DD, 1, stream);
  }

  f2bf<<<(M * DD / 8) / 256, 256, 0, stream>>>(h, ybf);
  // logits = h @ logit_w + logit_b  (8-phase)
  G256<4>(ybf, DD, logT, DD, out, VV, logit_b, M, VV, DD, stream);
}

// Round 3
// 1613.150 us; speedup vs baseline: 1.1134x; 1.0044x over previous
//
#include <hip/hip_runtime.h>

#define DD 1024
#define LL 4
#define HH 8
#define BB 2
#define TT 2048
#define VV 32000
#define SCALE_QK 0.08838834764831845f

typedef __bf16 bf16x8 __attribute__((ext_vector_type(8)));
typedef __bf16 bf16x4 __attribute__((ext_vector_type(4)));
typedef float  f32x4  __attribute__((ext_vector_type(4)));

__device__ __forceinline__ void gload_lds16(const void* g, void* l) {
  __builtin_amdgcn_global_load_lds((const __attribute__((address_space(1))) void*)g,
                                   (__attribute__((address_space(3))) void*)l, 16, 0, 0);
}

// =====================================================================
// 256x256 8-phase GEMM (T1+T2+T3+T4+T5): C[M,N] = A[M,K] * Bt[N,K]^T
// MODE 0: C bf16 plain ; MODE 3: C bf16 = leakyrelu(acc+bias) ; MODE 4: C f32 = acc+bias
// LDS 128 KiB dynamic: A ring4 x 16KB at [0,64K), B ring4 at [64K,128K)
// unit u = 2*t + ksub, slot = u & 3.  De-pinned schedule (m141/m201 lesson):
// plain s_barrier; lgkmcnt(0)+sched_barrier(0) only before MFMA cluster.
// =====================================================================
template<int MODE>
__global__ __launch_bounds__(512, 2)
void gemm256(const __bf16* __restrict__ A, long ldA,
             const __bf16* __restrict__ Bt, long ldB,
             void* __restrict__ Cv, long ldC,
             const float* __restrict__ bias,
             int K, int nby)
{
  extern __shared__ __attribute__((aligned(16))) char smem[];

  // T1: bijective XCD swizzle, column-major inner (consecutive ids share B-panel)
  const int nwg = gridDim.x;
  const int o = blockIdx.x;
  const int q8 = nwg >> 3, r8 = nwg & 7;
  const int xcd = o & 7, idx = o >> 3;
  const int swz = (xcd < r8 ? xcd * (q8 + 1) : r8 * (q8 + 1) + (xcd - r8) * q8) + idx;
  const int bx = swz / nby, by = swz - bx * nby;
  const int m0 = by * 256, n0 = bx * 256;

  const int tid = threadIdx.x;
  const int wv = tid >> 6, ln = tid & 63;
  const int wm = wv >> 2, wn = wv & 3;

  // staging: per-lane pre-swizzled global source (rule 21)
  const int u = (ln & 7) ^ (ln >> 3);
  const int dR = u >> 2;
  const int dK = (u & 3) << 3;
  const int row0 = (wv * 16 + (ln >> 3)) * 2 + dR;
  const __bf16* aS0 = A  + (size_t)(m0 + row0) * ldA + dK;
  const __bf16* aS1 = A  + (size_t)(m0 + row0 + 16) * ldA + dK;
  const __bf16* bS0 = Bt + (size_t)(n0 + row0) * ldB + dK;
  const __bf16* bS1 = Bt + (size_t)(n0 + row0 + 16) * ldB + dK;
  char* const dBase = smem + wv * 2048 + ln * 16;

  // fragment read offsets (conflict-free: 8 lanes per bank-group)
  const int lr = ln & 15;
  const int gfr = ((((ln & 1) << 2) | ((ln >> 4) & 3)) ^ ((ln >> 1) & 7)) << 4;
  const int aRd = (wm * 64 + (lr >> 1)) * 128 + gfr;
  const int bRd = 65536 + (wn * 32 + (lr >> 1)) * 128 + gfr;

  f32x4 acc[8][4] = {};
  bf16x8 b[4];
  const int NT = K >> 6;

#define STG_A(tt, ks) { const int sl = ((2*(tt)+(ks)) & 3) * 16384; \
    gload_lds16(aS0 + (tt)*64 + (ks)*32, dBase + sl); \
    gload_lds16(aS1 + (tt)*64 + (ks)*32, dBase + sl + 1024); }
#define STG_B(tt, ks) { const int sl = ((2*(tt)+(ks)) & 3) * 16384 + 65536; \
    gload_lds16(bS0 + (tt)*64 + (ks)*32, dBase + sl); \
    gload_lds16(bS1 + (tt)*64 + (ks)*32, dBase + sl + 1024); }
#define BAR() __builtin_amdgcn_s_barrier()
#define PREMFMA() { asm volatile("s_waitcnt lgkmcnt(0)" ::: "memory"); __builtin_amdgcn_sched_barrier(0); }
#define MFMA_Q(MH) \
    __builtin_amdgcn_s_setprio(1); \
    _Pragma("unroll") \
    for (int i = 0; i < 4; i++) \
      _Pragma("unroll") \
      for (int j = 0; j < 4; j++) \
        acc[(MH)*4+i][j] = __builtin_amdgcn_mfma_f32_16x16x32_bf16(a[i], b[j], acc[(MH)*4+i][j], 0,0,0); \
    __builtin_amdgcn_s_setprio(0);

  // prologue: units 0,1 (tile0) + unit 2 (tile1,k0); allow unit2's 4 loads in flight
  STG_A(0, 0); STG_B(0, 0); STG_A(0, 1); STG_B(0, 1);
  if (NT > 1) {
    STG_A(1, 0); STG_B(1, 0);
    asm volatile("s_waitcnt vmcnt(4)" ::: "memory");
  } else {
    asm volatile("s_waitcnt vmcnt(0)" ::: "memory");
  }
  BAR();

  for (int t = 0; t < NT; ++t) {
    const char* uA0 = smem + ((2 * t) & 3) * 16384;
    const char* uA1 = smem + ((2 * t + 1) & 3) * 16384;
    bf16x8 a[4];
    // ---- p0: m-half0, ksub0 ----
#pragma unroll
    for (int i = 0; i < 4; i++) a[i] = *(const bf16x8*)(uA0 + aRd + i * 1024);
#pragma unroll
    for (int j = 0; j < 4; j++) b[j] = *(const bf16x8*)(uA0 + bRd + j * 1024);
    if (t + 1 < NT) STG_A(t + 1, 1);
    BAR();
    PREMFMA();
    MFMA_Q(0);
    BAR();
    // ---- p1: m-half1, ksub0 (B regs reused) ----
#pragma unroll
    for (int i = 0; i < 4; i++) a[i] = *(const bf16x8*)(uA0 + aRd + (4 + i) * 1024);
    if (t + 1 < NT) STG_B(t + 1, 1);
    BAR();
    PREMFMA();
    MFMA_Q(1);
    BAR();
    // ---- p2: m-half0, ksub1 ----
#pragma unroll
    for (int i = 0; i < 4; i++) a[i] = *(const bf16x8*)(uA1 + aRd + i * 1024);
#pragma unroll
    for (int j = 0; j < 4; j++) b[j] = *(const bf16x8*)(uA1 + bRd + j * 1024);
    if (t + 2 < NT) STG_A(t + 2, 0);
    BAR();
    PREMFMA();
    MFMA_Q(0);
    BAR();
    // ---- p3: m-half1, ksub1 ----
#pragma unroll
    for (int i = 0; i < 4; i++) a[i] = *(const bf16x8*)(uA1 + aRd + (4 + i) * 1024);
    if (t + 2 < NT) STG_B(t + 2, 0);
    BAR();
    PREMFMA();
    MFMA_Q(1);
    // boundary: ensure tile t+1's 4 units landed; allow unit-(2t+4)'s 4 loads in flight
    if (t + 2 < NT)      { asm volatile("s_waitcnt vmcnt(4)" ::: "memory"); }
    else if (t + 1 < NT) { asm volatile("s_waitcnt vmcnt(0)" ::: "memory"); }
    BAR();
  }
#undef STG_A
#undef STG_B
#undef BAR
#undef PREMFMA
#undef MFMA_Q

  // epilogue
  const int rb = m0 + wm * 128 + (ln >> 4) * 4;
  const int cb = n0 + wn * 64 + (ln & 15);
#pragma unroll
  for (int i = 0; i < 8; i++)
#pragma unroll
    for (int j = 0; j < 4; j++) {
      const int col = cb + j * 16;
#pragma unroll
      for (int r = 0; r < 4; r++) {
        const int row = rb + i * 16 + r;
        float v = acc[i][j][r];
        const size_t ci = (size_t)row * ldC + col;
        if (MODE == 0)      ((__bf16*)Cv)[ci] = (__bf16)v;
        else if (MODE == 3) { v += bias[col]; ((__bf16*)Cv)[ci] = (__bf16)(v >= 0.f ? v : 0.01f * v); }
        else if (MODE == 4) ((float*)Cv)[ci] = v + bias[col];
      }
    }
}

// ---------------- legacy 128x128 NT GEMM ----------------
// MODE 0: C bf16 ; MODE 1: C f32 ; MODE 2: C f32 = acc+bias+res ; MODE 5: f32 atomicAdd (split-K, z=(kc<<4)|bh)
template<int MODE>
__global__ __launch_bounds__(256)
void gemm_nt(const __bf16* __restrict__ A, long ldA, long aSB, long aSH,
             const __bf16* __restrict__ Bt, long ldB, long bSB, long bSH,
             void* __restrict__ Cv, long ldC, long cSB, long cSH,
             const float* __restrict__ bias,
             const float* __restrict__ res, long ldR,
             int K)
{
  int zbh = blockIdx.z;
  if (MODE == 5) {
    const int kc = zbh >> 4;
    zbh &= 15;
    A  += (size_t)kc * K;   // K here = chunk length; chunks contiguous along K
    Bt += (size_t)kc * K;
  }
  const int zb = zbh >> 3, zh = zbh & 7;
  A  += (size_t)zb * aSB + (size_t)zh * aSH;
  Bt += (size_t)zb * bSB + (size_t)zh * bSH;
  const size_t cOff = (size_t)zb * cSB + (size_t)zh * cSH;

  __shared__ __attribute__((aligned(16))) __bf16 As[128 * 32];
  __shared__ __attribute__((aligned(16))) __bf16 Bs[128 * 32];

  const int tid = threadIdx.x;
  const int wv = tid >> 6, ln = tid & 63;
  const int m0 = blockIdx.y * 128, n0 = blockIdx.x * 128;
  const int wr = (wv >> 1) * 64, wc = (wv & 1) * 64;
  const int lr = ln & 15, lk = (ln >> 4) * 8;
  const int srow = wv * 16 + (ln >> 2);
  const int skel = (ln & 3) * 8;

  f32x4 acc[4][4] = {};

  for (int k0 = 0; k0 < K; k0 += 32) {
    __syncthreads();
    gload_lds16(A  + (size_t)(m0      + srow) * ldA + k0 + skel, (char*)As +        wv * 1024 + ln * 16);
    gload_lds16(A  + (size_t)(m0 + 64 + srow) * ldA + k0 + skel, (char*)As + 4096 + wv * 1024 + ln * 16);
    gload_lds16(Bt + (size_t)(n0      + srow) * ldB + k0 + skel, (char*)Bs +        wv * 1024 + ln * 16);
    gload_lds16(Bt + (size_t)(n0 + 64 + srow) * ldB + k0 + skel, (char*)Bs + 4096 + wv * 1024 + ln * 16);
    __syncthreads();
    bf16x8 af[4], bfr[4];
#pragma unroll
    for (int i = 0; i < 4; i++) af[i]  = *(const bf16x8*)&As[(wr + i * 16 + lr) * 32 + lk];
#pragma unroll
    for (int i = 0; i < 4; i++) bfr[i] = *(const bf16x8*)&Bs[(wc + i * 16 + lr) * 32 + lk];
#pragma unroll
    for (int i = 0; i < 4; i++)
#pragma unroll
      for (int j = 0; j < 4; j++)
        acc[i][j] = __builtin_amdgcn_mfma_f32_16x16x32_bf16(af[i], bfr[j], acc[i][j], 0, 0, 0);
  }

  const int rb = m0 + wr + (ln >> 4) * 4;
  const int cb = n0 + wc + (ln & 15);
#pragma unroll
  for (int i = 0; i < 4; i++)
#pragma unroll
    for (int j = 0; j < 4; j++) {
      const int col = cb + j * 16;
#pragma unroll
      for (int r = 0; r < 4; r++) {
        const int row = rb + i * 16 + r;
        float v = acc[i][j][r];
        const size_t ci = cOff + (size_t)row * ldC + col;
        if (MODE == 0)      ((__bf16*)Cv)[ci] = (__bf16)v;
        else if (MODE == 1) ((float*)Cv)[ci] = v;
        else if (MODE == 2) ((float*)Cv)[ci] = v + bias[col] + res[(size_t)row * ldR + col];
        else if (MODE == 5) atomicAdd(&((float*)Cv)[ci], v);
      }
    }
}

// ---------------- weight transpose + fp32->bf16 ----------------
__global__ void wtrans(const float* __restrict__ W, __bf16* __restrict__ Wt, int K, int N)
{
  const size_t zo = (size_t)blockIdx.z * K * N;
  __shared__ float t[32][33];
  const int n0 = blockIdx.x * 32, k0 = blockIdx.y * 32;
  const int tx = threadIdx.x, ty = threadIdx.y;
#pragma unroll
  for (int r = 0; r < 4; r++)
    t[ty + r * 8][tx] = W[zo + (size_t)(k0 + ty + r * 8) * N + n0 + tx];
  __syncthreads();
#pragma unroll
  for (int r = 0; r < 4; r++)
    Wt[zo + (size_t)(n0 + ty + r * 8) * K + k0 + tx] = (__bf16)t[tx][ty + r * 8];
}

// ---------------- V transpose per (b,h) ----------------
__global__ void vtrans(const __bf16* __restrict__ qkv, __bf16* __restrict__ Vt)
{
  const int z = blockIdx.z, bb = z >> 3, hh = z & 7;
  const __bf16* src = qkv + ((size_t)bb * TT + hh) * (3 * DD) + 2 * DD;
  __bf16* dst = Vt + (size_t)z * DD * 256;
  __shared__ __bf16 t[32][33];
  const int n0 = blockIdx.x * 32, i0 = blockIdx.y * 32;
  const int tx = threadIdx.x, ty = threadIdx.y;
#pragma unroll
  for (int r = 0; r < 4; r++)
    t[ty + r * 8][tx] = src[(size_t)(i0 + ty + r * 8) * (HH * 3 * DD) + n0 + tx];
  __syncthreads();
#pragma unroll
  for (int r = 0; r < 4; r++)
    dst[(size_t)(n0 + ty + r * 8) * 256 + i0 + tx] = t[tx][ty + r * 8];
}

// ---------------- embedding gather ----------------
__global__ void embed_k(const int* __restrict__ x, const float* __restrict__ emb, float* __restrict__ h)
{
  const int row = blockIdx.x;
  const int tok = x[row];
  ((float4*)(h + (size_t)row * DD))[threadIdx.x] = ((const float4*)(emb + (size_t)tok * DD))[threadIdx.x];
}

// ---------------- layernorm row -> bf16 ----------------
__global__ void ln_rows(const float* __restrict__ x, const float* __restrict__ g,
                        const float* __restrict__ b, __bf16* __restrict__ y)
{
  const int row = blockIdx.x, t = threadIdx.x;
  const int wv = t >> 6, ln = t & 63;
  const float4 v = ((const float4*)(x + (size_t)row * DD))[t];
  float s  = v.x + v.y + v.z + v.w;
  float ss = v.x * v.x + v.y * v.y + v.z * v.z + v.w * v.w;
#pragma unroll
  for (int o = 32; o; o >>= 1) { s += __shfl_xor(s, o); ss += __shfl_xor(ss, o); }
  __shared__ float rs_[4], rss_[4];
  if (!ln) { rs_[wv] = s; rss_[wv] = ss; }
  __syncthreads();
  s  = rs_[0] + rs_[1] + rs_[2] + rs_[3];
  ss = rss_[0] + rss_[1] + rss_[2] + rss_[3];
  const float mu  = s * (1.0f / DD);
  const float var = ss * (1.0f / DD) - mu * mu;
  const float r   = rsqrtf(var + 1e-5f);
  const float4 gv = ((const float4*)g)[t];
  const float4 bv = ((const float4*)b)[t];
  bf16x4 o = { (__bf16)((v.x - mu) * r * gv.x + bv.x),
               (__bf16)((v.y - mu) * r * gv.y + bv.y),
               (__bf16)((v.z - mu) * r * gv.z + bv.z),
               (__bf16)((v.w - mu) * r * gv.w + bv.w) };
  ((bf16x4*)(y + (size_t)row * DD))[t] = o;
}

// ---------------- softmax over 256-wide rows -> bf16 ----------------
__global__ void softmax256(const float* __restrict__ S, __bf16* __restrict__ P)
{
  const int row = blockIdx.x, t = threadIdx.x;
  const int wv = t >> 6, ln = t & 63;
  const float v = S[(size_t)row * 256 + t] * SCALE_QK;
  float m = v;
#pragma unroll
  for (int o = 32; o; o >>= 1) m = fmaxf(m, __shfl_xor(m, o));
  __shared__ float red[8];
  if (!ln) red[wv] = m;
  __syncthreads();
  m = fmaxf(fmaxf(red[0], red[1]), fmaxf(red[2], red[3]));
  const float e = __expf(v - m);
  float s = e;
#pragma unroll
  for (int o = 32; o; o >>= 1) s += __shfl_xor(s, o);
  if (!ln) red[4 + wv] = s;
  __syncthreads();
  s = red[4] + red[5] + red[6] + red[7];
  P[(size_t)row * 256 + t] = (__bf16)(e / s);
}

// ---------------- fp32 -> bf16 convert ----------------
__global__ void f2bf(const float* __restrict__ h, __bf16* __restrict__ y)
{
  const size_t i = (size_t)blockIdx.x * 256 + threadIdx.x;
  const float4 a = ((const float4*)h)[2 * i];
  const float4 b = ((const float4*)h)[2 * i + 1];
  bf16x8 o = { (__bf16)a.x, (__bf16)a.y, (__bf16)a.z, (__bf16)a.w,
               (__bf16)b.x, (__bf16)b.y, (__bf16)b.z, (__bf16)b.w };
  ((bf16x8*)y)[i] = o;
}

template<int MODE>
static void G(const __bf16* A, long ldA, long aSB, long aSH,
              const __bf16* Bt, long ldB, long bSB, long bSH,
              void* C, long ldC, long cSB, long cSH,
              const float* bias, const float* res, long ldR,
              int M, int N, int K, int Z, hipStream_t s)
{
  gemm_nt<MODE><<<dim3(N / 128, M / 128, Z), 256, 0, s>>>(
      A, ldA, aSB, aSH, Bt, ldB, bSB, bSH, C, ldC, cSB, cSH, bias, res, ldR, K);
}

template<int MODE>
static void G256(const __bf16* A, long ldA, const __bf16* Bt, long ldB,
                 void* C, long ldC, const float* bias,
                 int M, int N, int K, hipStream_t s)
{
  hipFuncSetAttribute((const void*)gemm256<MODE>,
                      hipFuncAttributeMaxDynamicSharedMemorySize, 131072);
  const int nby = M / 256, nbx = N / 256;
  gemm256<MODE><<<dim3(nbx * nby), 512, 131072, s>>>(A, ldA, Bt, ldB, C, ldC, bias, K, nby);
}

extern "C" void kernel_launch(void* const* d_in, const int* in_sizes, int n_in,
                              void* d_out, int out_size, void* d_ws, size_t ws_size,
                              hipStream_t stream)
{
  const int*   x       = (const int*)  d_in[0];
  const float* emb     = (const float*)d_in[1];
  const float* ln1_g   = (const float*)d_in[2];
  const float* ln1_b   = (const float*)d_in[3];
  const float* wqkv    = (const float*)d_in[4];
  const float* wout_w  = (const float*)d_in[5];
  const float* wout_b  = (const float*)d_in[6];
  const float* ln2_g   = (const float*)d_in[7];
  const float* ln2_b   = (const float*)d_in[8];
  const float* ff1_w   = (const float*)d_in[9];
  const float* ff1_b   = (const float*)d_in[10];
  const float* ff2_w   = (const float*)d_in[11];
  const float* ff2_b   = (const float*)d_in[12];
  const float* logit_w = (const float*)d_in[13];
  const float* logit_b = (const float*)d_in[14];
  float* out = (float*)d_out;

  char* w = (char*)d_ws;
  size_t off = 0;
  auto take = [&](size_t bytes) { void* p = w + off; off += (bytes + 255) & ~(size_t)255; return p; };
  __bf16* wqkvT = (__bf16*)take((size_t)LL * 3 * DD * DD * 2);
  __bf16* woutT = (__bf16*)take((size_t)LL * DD * DD * 2);
  __bf16* ff1T  = (__bf16*)take((size_t)LL * 4 * DD * DD * 2);
  __bf16* ff2T  = (__bf16*)take((size_t)LL * DD * 4 * DD * 2);
  __bf16* logT  = (__bf16*)take((size_t)VV * DD * 2);
  float*  h     = (float*) take((size_t)BB * TT * DD * 4);
  __bf16* ybf   = (__bf16*)take((size_t)BB * TT * DD * 2);
  __bf16* qkvbf = (__bf16*)take((size_t)BB * TT * 3 * DD * 2);
  float*  Smat  = (float*) take((size_t)BB * HH * 256 * 256 * 4);
  __bf16* Pbf   = (__bf16*)take((size_t)BB * HH * 256 * 256 * 2);
  __bf16* Vt    = (__bf16*)take((size_t)BB * HH * DD * 256 * 2);
  __bf16* Obf   = (__bf16*)take((size_t)BB * TT * DD * 2);
  __bf16* midbf = (__bf16*)take((size_t)BB * TT * 4 * DD * 2);
  if (ws_size < off) return;

  const dim3 tb(32, 8);
  wtrans<<<dim3(3 * DD / 32, DD / 32, LL), tb, 0, stream>>>(wqkv,   wqkvT, DD, 3 * DD);
  wtrans<<<dim3(DD / 32,     DD / 32, LL), tb, 0, stream>>>(wout_w, woutT, DD, DD);
  wtrans<<<dim3(4 * DD / 32, DD / 32, LL), tb, 0, stream>>>(ff1_w,  ff1T,  DD, 4 * DD);
  wtrans<<<dim3(DD / 32, 4 * DD / 32, LL), tb, 0, stream>>>(ff2_w,  ff2T,  4 * DD, DD);
  wtrans<<<dim3(VV / 32,     DD / 32, 1),  tb, 0, stream>>>(logit_w, logT, DD, VV);

  const int M = BB * TT;
  embed_k<<<M, 256, 0, stream>>>(x, emb, h);

  for (int l = 0; l < LL; l++) {
    ln_rows<<<M, 256, 0, stream>>>(h, ln1_g + l * DD, ln1_b + l * DD, ybf);
    // qkv = y @ wqkv  (8-phase)
    G256<0>(ybf, DD, wqkvT + (size_t)l * 3 * DD * DD, DD,
            qkvbf, 3 * DD, nullptr, M, 3 * DD, DD, stream);
    // S = Q @ K^T  (split-K x4, atomic accumulate into zeroed Smat)
    hipMemsetAsync(Smat, 0, (size_t)BB * HH * 256 * 256 * 4, stream);
    G<5>(qkvbf, HH * 3 * DD, (long)TT * 3 * DD, 3 * DD,
         qkvbf + DD, HH * 3 * DD, (long)TT * 3 * DD, 3 * DD,
         Smat, 256, (long)HH * 256 * 256, 256 * 256,
         nullptr, nullptr, 0, 256, 256, DD / 4, 4 * BB * HH, stream);
    softmax256<<<BB * HH * 256, 256, 0, stream>>>(Smat, Pbf);
    vtrans<<<dim3(DD / 32, 256 / 32, BB * HH), tb, 0, stream>>>(qkvbf, Vt);
    // O = P @ V
    G<0>(Pbf, 256, (long)HH * 256 * 256, 256 * 256,
         Vt, 256, (long)HH * DD * 256, (long)DD * 256,
         Obf, HH * DD, (long)TT * DD, DD,
         nullptr, nullptr, 0, 256, DD, 256, BB * HH, stream);
    // h += O @ wout + b  (N=1024 -> legacy tile)
    G<2>(Obf, DD, 0, 0, woutT + (size_t)l * DD * DD, DD, 0, 0,
         h, DD, 0, 0, wout_b + l * DD, h, DD, M, DD, DD, 1, stream);
    ln_rows<<<M, 256, 0, stream>>>(h, ln2_g + l * DD, ln2_b + l * DD, ybf);
    // mid = lrelu(y @ ff1 + b1)  (8-phase)
    G256<3>(ybf, DD, ff1T + (size_t)l * 4 * DD * DD, DD,
            midbf, 4 * DD, ff1_b + (size_t)l * 4 * DD, M, 4 * DD, DD, stream);
    // h += mid @ ff2 + b2  (N=1024 -> legacy tile)
    G<2>(midbf, 4 * DD, 0, 0, ff2T + (size_t)l * DD * 4 * DD, 4 * DD, 0, 0,
         h, DD, 0, 0, ff2_b + l * DD, h, DD, M, DD, 4 * DD, 1, stream);
  }

  f2bf<<<(M * DD / 8) / 256, 256, 0, stream>>>(h, ybf);
  // logits = h @ logit_w + logit_b  (8-phase)
  G256<4>(ybf, DD, logT, DD, out, VV, logit_b, M, VV, DD, stream);
}

// Round 5
// 1538.329 us; speedup vs baseline: 1.1676x; 1.0486x over previous
//
#include <hip/hip_runtime.h>

#define DD 1024
#define LL 4
#define HH 8
#define BB 2
#define TT 2048
#define VV 32000
#define SCALE_QK 0.08838834764831845f

typedef __bf16 bf16x8 __attribute__((ext_vector_type(8)));
typedef __bf16 bf16x4 __attribute__((ext_vector_type(4)));
typedef float  f32x4  __attribute__((ext_vector_type(4)));

__device__ __forceinline__ void gload_lds16(const void* g, void* l) {
  __builtin_amdgcn_global_load_lds((const __attribute__((address_space(1))) void*)g,
                                   (__attribute__((address_space(3))) void*)l, 16, 0, 0);
}

// =====================================================================
// ring3 counted-vmcnt NT GEMM: C[M,N] = A[M,K] * Bt[N,K]^T (+epilogue)
// BM=BN=128, BK=32, 256 threads (4 waves 2m x 2n), LDS 48 KiB static
//   A slots: 3 x 8 KiB @ [0,24K) ; B slots: 3 x 8 KiB @ [24K,48K)
// Per K-step t: stage slot (t+2)%3, read slot t%3 (8x ds_read_b128,
// T2-swizzled, 0-conflict), 16 MFMA, vmcnt(4) [counted: stage(t+1) is
// the oldest 4, stage(t+2) stays in flight], one plain s_barrier.
// Slot (t+2)%3 == slot read at t-1: its data was consumed into regs
// (lgkm-waited before MFMA) before the t-1 barrier -> overwrite safe.
// MODE 0: bf16 ; 1: f32 ; 2: f32 acc+bias+res ; 3: bf16 lrelu(acc+bias) ;
// MODE 4: f32 acc+bias ; 5: f32 atomicAdd (split-K, z=(kc<<4)|bh)
// =====================================================================
template<int MODE>
__global__ __launch_bounds__(256, 3)
void gemm_rt(const __bf16* __restrict__ A, long ldA, long aSB, long aSH,
             const __bf16* __restrict__ Bt, long ldB, long bSB, long bSH,
             void* __restrict__ Cv, long ldC, long cSB, long cSH,
             const float* __restrict__ bias,
             const float* __restrict__ res, long ldR,
             int K)
{
  int zbh = blockIdx.z;
  if (MODE == 5) {
    const int kc = zbh >> 4;
    zbh &= 15;
    A  += (size_t)kc * K;
    Bt += (size_t)kc * K;
  }
  const int zb = zbh >> 3, zh = zbh & 7;
  A  += (size_t)zb * aSB + (size_t)zh * aSH;
  Bt += (size_t)zb * bSB + (size_t)zh * bSH;
  const size_t cOff = (size_t)zb * cSB + (size_t)zh * cSH;

  // T1: bijective XCD swizzle on flattened (x,y); column-major decode so
  // consecutive swz on one XCD share the B-panel.
  const int nbx = gridDim.x, nby = gridDim.y;
  const int nwg = nbx * nby;
  const int fid = blockIdx.y * nbx + blockIdx.x;
  const int q8 = nwg >> 3, r8 = nwg & 7;
  const int xcd = fid & 7, idx = fid >> 3;
  const int swz = (xcd < r8 ? xcd * (q8 + 1) : r8 * (q8 + 1) + (xcd - r8) * q8) + idx;
  const int bx = swz / nby, by = swz - bx * nby;
  const int m0 = by * 128, n0 = bx * 128;

  __shared__ __attribute__((aligned(16))) char smem[49152];

  const int tid = threadIdx.x;
  const int wv = tid >> 6, ln = tid & 63;
  const int wm = wv >> 1, wn = wv & 1;

  // staging geometry (T2 content swizzle; unit = 64 lines x 128 B):
  // physical (line, granule g) holds logical row = 2*line + (u>>2),
  // kgrp = u&3 (8 bf16), u = g ^ (line&7). Realized by pre-swizzling the
  // per-lane GLOBAL source; LDS dest stays linear (rule 21).
  const int ls = tid >> 3;            // line 0..31 (first half of unit)
  const int gs = tid & 7;
  const int us = gs ^ (ls & 7);
  const int rs = 2 * ls + (us >> 2);  // row 0..63
  const int ks = (us & 3) * 8;
  const __bf16* pA0 = A  + (size_t)(m0 + rs) * ldA + ks;
  const __bf16* pA1 = A  + (size_t)(m0 + 64 + rs) * ldA + ks;   // lines 32..63
  const __bf16* pB0 = Bt + (size_t)(n0 + rs) * ldB + ks;
  const __bf16* pB1 = Bt + (size_t)(n0 + 64 + rs) * ldB + ks;

  // fragment read offsets (0-conflict: 8 lanes per 128B line spread all 32 banks)
  const int lr = ln & 15;
  const int gfr = ((((ln & 1) << 2) | ((ln >> 4) & 3)) ^ ((ln >> 1) & 7)) << 4;
  const int aR = (wm * 32 + (lr >> 1)) * 128 + gfr;           // + i*1024
  const int bR = 24576 + (wn * 32 + (lr >> 1)) * 128 + gfr;   // + j*1024

  f32x4 acc[4][4] = {};
  const int NT = K >> 5;

#define STG(sl) { \
    char* da = smem + (sl) * 8192 + tid * 16; \
    gload_lds16(pA0, da); gload_lds16(pA1, da + 4096); \
    char* db = da + 24576; \
    gload_lds16(pB0, db); gload_lds16(pB1, db + 4096); \
    pA0 += 32; pA1 += 32; pB0 += 32; pB1 += 32; }

  // prologue: stage tiles 0,1; wait tile 0 (oldest 4), leave tile 1 in flight
  STG(0);
  if (NT > 1) {
    STG(1);
    asm volatile("s_waitcnt vmcnt(4)" ::: "memory");
  } else {
    asm volatile("s_waitcnt vmcnt(0)" ::: "memory");
  }
  __builtin_amdgcn_s_barrier();

  int sc = 0, sn = 1, sf = 2;
  for (int t = 0; t < NT; ++t) {
    if (t + 2 < NT) STG(sf);
    const char* ba = smem + sc * 8192;
    bf16x8 a[4], b[4];
#pragma unroll
    for (int i = 0; i < 4; i++) a[i] = *(const bf16x8*)(ba + aR + i * 1024);
#pragma unroll
    for (int j = 0; j < 4; j++) b[j] = *(const bf16x8*)(ba + bR + j * 1024);
    __builtin_amdgcn_s_setprio(1);
#pragma unroll
    for (int i = 0; i < 4; i++)
#pragma unroll
      for (int j = 0; j < 4; j++)
        acc[i][j] = __builtin_amdgcn_mfma_f32_16x16x32_bf16(a[i], b[j], acc[i][j], 0, 0, 0);
    __builtin_amdgcn_s_setprio(0);
    if (t + 1 < NT) {
      if (t + 2 < NT) { asm volatile("s_waitcnt vmcnt(4)" ::: "memory"); }
      else            { asm volatile("s_waitcnt vmcnt(0)" ::: "memory"); }
      __builtin_amdgcn_sched_barrier(0);
      __builtin_amdgcn_s_barrier();
    }
    const int tmp = sc; sc = sn; sn = sf; sf = tmp;
  }
#undef STG

  // epilogue (verified C/D mapping: col=lane&15, row=(lane>>4)*4+reg)
  const int rb = m0 + wm * 64 + (ln >> 4) * 4;
  const int cb = n0 + wn * 64 + (ln & 15);
#pragma unroll
  for (int i = 0; i < 4; i++)
#pragma unroll
    for (int j = 0; j < 4; j++) {
      const int col = cb + j * 16;
#pragma unroll
      for (int r = 0; r < 4; r++) {
        const int row = rb + i * 16 + r;
        float v = acc[i][j][r];
        const size_t ci = cOff + (size_t)row * ldC + col;
        if (MODE == 0)      ((__bf16*)Cv)[ci] = (__bf16)v;
        else if (MODE == 1) ((float*)Cv)[ci] = v;
        else if (MODE == 2) ((float*)Cv)[ci] = v + bias[col] + res[(size_t)row * ldR + col];
        else if (MODE == 3) { v += bias[col]; ((__bf16*)Cv)[ci] = (__bf16)(v >= 0.f ? v : 0.01f * v); }
        else if (MODE == 4) ((float*)Cv)[ci] = v + bias[col];
        else if (MODE == 5) atomicAdd(&((float*)Cv)[ci], v);
      }
    }
}

// ---------------- weight transpose + fp32->bf16 ----------------
__global__ void wtrans(const float* __restrict__ W, __bf16* __restrict__ Wt, int K, int N)
{
  const size_t zo = (size_t)blockIdx.z * K * N;
  __shared__ float t[32][33];
  const int n0 = blockIdx.x * 32, k0 = blockIdx.y * 32;
  const int tx = threadIdx.x, ty = threadIdx.y;
#pragma unroll
  for (int r = 0; r < 4; r++)
    t[ty + r * 8][tx] = W[zo + (size_t)(k0 + ty + r * 8) * N + n0 + tx];
  __syncthreads();
#pragma unroll
  for (int r = 0; r < 4; r++)
    Wt[zo + (size_t)(n0 + ty + r * 8) * K + k0 + tx] = (__bf16)t[tx][ty + r * 8];
}

// ---------------- V transpose per (b,h) ----------------
__global__ void vtrans(const __bf16* __restrict__ qkv, __bf16* __restrict__ Vt)
{
  const int z = blockIdx.z, bb = z >> 3, hh = z & 7;
  const __bf16* src = qkv + ((size_t)bb * TT + hh) * (3 * DD) + 2 * DD;
  __bf16* dst = Vt + (size_t)z * DD * 256;
  __shared__ __bf16 t[32][33];
  const int n0 = blockIdx.x * 32, i0 = blockIdx.y * 32;
  const int tx = threadIdx.x, ty = threadIdx.y;
#pragma unroll
  for (int r = 0; r < 4; r++)
    t[ty + r * 8][tx] = src[(size_t)(i0 + ty + r * 8) * (HH * 3 * DD) + n0 + tx];
  __syncthreads();
#pragma unroll
  for (int r = 0; r < 4; r++)
    dst[(size_t)(n0 + ty + r * 8) * 256 + i0 + tx] = t[tx][ty + r * 8];
}

// ---------------- embedding gather ----------------
__global__ void embed_k(const int* __restrict__ x, const float* __restrict__ emb, float* __restrict__ h)
{
  const int row = blockIdx.x;
  const int tok = x[row];
  ((float4*)(h + (size_t)row * DD))[threadIdx.x] = ((const float4*)(emb + (size_t)tok * DD))[threadIdx.x];
}

// ---------------- layernorm row -> bf16 ----------------
__global__ void ln_rows(const float* __restrict__ x, const float* __restrict__ g,
                        const float* __restrict__ b, __bf16* __restrict__ y)
{
  const int row = blockIdx.x, t = threadIdx.x;
  const int wv = t >> 6, ln = t & 63;
  const float4 v = ((const float4*)(x + (size_t)row * DD))[t];
  float s  = v.x + v.y + v.z + v.w;
  float ss = v.x * v.x + v.y * v.y + v.z * v.z + v.w * v.w;
#pragma unroll
  for (int o = 32; o; o >>= 1) { s += __shfl_xor(s, o); ss += __shfl_xor(ss, o); }
  __shared__ float rs_[4], rss_[4];
  if (!ln) { rs_[wv] = s; rss_[wv] = ss; }
  __syncthreads();
  s  = rs_[0] + rs_[1] + rs_[2] + rs_[3];
  ss = rss_[0] + rss_[1] + rss_[2] + rss_[3];
  const float mu  = s * (1.0f / DD);
  const float var = ss * (1.0f / DD) - mu * mu;
  const float r   = rsqrtf(var + 1e-5f);
  const float4 gv = ((const float4*)g)[t];
  const float4 bv = ((const float4*)b)[t];
  bf16x4 o = { (__bf16)((v.x - mu) * r * gv.x + bv.x),
               (__bf16)((v.y - mu) * r * gv.y + bv.y),
               (__bf16)((v.z - mu) * r * gv.z + bv.z),
               (__bf16)((v.w - mu) * r * gv.w + bv.w) };
  ((bf16x4*)(y + (size_t)row * DD))[t] = o;
}

// ---------------- softmax over 256-wide rows -> bf16 ----------------
__global__ void softmax256(const float* __restrict__ S, __bf16* __restrict__ P)
{
  const int row = blockIdx.x, t = threadIdx.x;
  const int wv = t >> 6, ln = t & 63;
  const float v = S[(size_t)row * 256 + t] * SCALE_QK;
  float m = v;
#pragma unroll
  for (int o = 32; o; o >>= 1) m = fmaxf(m, __shfl_xor(m, o));
  __shared__ float red[8];
  if (!ln) red[wv] = m;
  __syncthreads();
  m = fmaxf(fmaxf(red[0], red[1]), fmaxf(red[2], red[3]));
  const float e = __expf(v - m);
  float s = e;
#pragma unroll
  for (int o = 32; o; o >>= 1) s += __shfl_xor(s, o);
  if (!ln) red[4 + wv] = s;
  __syncthreads();
  s = red[4] + red[5] + red[6] + red[7];
  P[(size_t)row * 256 + t] = (__bf16)(e / s);
}

// ---------------- fp32 -> bf16 convert ----------------
__global__ void f2bf(const float* __restrict__ h, __bf16* __restrict__ y)
{
  const size_t i = (size_t)blockIdx.x * 256 + threadIdx.x;
  const float4 a = ((const float4*)h)[2 * i];
  const float4 b = ((const float4*)h)[2 * i + 1];
  bf16x8 o = { (__bf16)a.x, (__bf16)a.y, (__bf16)a.z, (__bf16)a.w,
               (__bf16)b.x, (__bf16)b.y, (__bf16)b.z, (__bf16)b.w };
  ((bf16x8*)y)[i] = o;
}

template<int MODE>
static void G(const __bf16* A, long ldA, long aSB, long aSH,
              const __bf16* Bt, long ldB, long bSB, long bSH,
              void* C, long ldC, long cSB, long cSH,
              const float* bias, const float* res, long ldR,
              int M, int N, int K, int Z, hipStream_t s)
{
  gemm_rt<MODE><<<dim3(N / 128, M / 128, Z), 256, 0, s>>>(
      A, ldA, aSB, aSH, Bt, ldB, bSB, bSH, C, ldC, cSB, cSH, bias, res, ldR, K);
}

extern "C" void kernel_launch(void* const* d_in, const int* in_sizes, int n_in,
                              void* d_out, int out_size, void* d_ws, size_t ws_size,
                              hipStream_t stream)
{
  const int*   x       = (const int*)  d_in[0];
  const float* emb     = (const float*)d_in[1];
  const float* ln1_g   = (const float*)d_in[2];
  const float* ln1_b   = (const float*)d_in[3];
  const float* wqkv    = (const float*)d_in[4];
  const float* wout_w  = (const float*)d_in[5];
  const float* wout_b  = (const float*)d_in[6];
  const float* ln2_g   = (const float*)d_in[7];
  const float* ln2_b   = (const float*)d_in[8];
  const float* ff1_w   = (const float*)d_in[9];
  const float* ff1_b   = (const float*)d_in[10];
  const float* ff2_w   = (const float*)d_in[11];
  const float* ff2_b   = (const float*)d_in[12];
  const float* logit_w = (const float*)d_in[13];
  const float* logit_b = (const float*)d_in[14];
  float* out = (float*)d_out;

  char* w = (char*)d_ws;
  size_t off = 0;
  auto take = [&](size_t bytes) { void* p = w + off; off += (bytes + 255) & ~(size_t)255; return p; };
  __bf16* wqkvT = (__bf16*)take((size_t)LL * 3 * DD * DD * 2);
  __bf16* woutT = (__bf16*)take((size_t)LL * DD * DD * 2);
  __bf16* ff1T  = (__bf16*)take((size_t)LL * 4 * DD * DD * 2);
  __bf16* ff2T  = (__bf16*)take((size_t)LL * DD * 4 * DD * 2);
  __bf16* logT  = (__bf16*)take((size_t)VV * DD * 2);
  float*  h     = (float*) take((size_t)BB * TT * DD * 4);
  __bf16* ybf   = (__bf16*)take((size_t)BB * TT * DD * 2);
  __bf16* qkvbf = (__bf16*)take((size_t)BB * TT * 3 * DD * 2);
  float*  Smat  = (float*) take((size_t)BB * HH * 256 * 256 * 4);
  __bf16* Pbf   = (__bf16*)take((size_t)BB * HH * 256 * 256 * 2);
  __bf16* Vt    = (__bf16*)take((size_t)BB * HH * DD * 256 * 2);
  __bf16* Obf   = (__bf16*)take((size_t)BB * TT * DD * 2);
  __bf16* midbf = (__bf16*)take((size_t)BB * TT * 4 * DD * 2);
  if (ws_size < off) return;

  const dim3 tb(32, 8);
  wtrans<<<dim3(3 * DD / 32, DD / 32, LL), tb, 0, stream>>>(wqkv,   wqkvT, DD, 3 * DD);
  wtrans<<<dim3(DD / 32,     DD / 32, LL), tb, 0, stream>>>(wout_w, woutT, DD, DD);
  wtrans<<<dim3(4 * DD / 32, DD / 32, LL), tb, 0, stream>>>(ff1_w,  ff1T,  DD, 4 * DD);
  wtrans<<<dim3(DD / 32, 4 * DD / 32, LL), tb, 0, stream>>>(ff2_w,  ff2T,  4 * DD, DD);
  wtrans<<<dim3(VV / 32,     DD / 32, 1),  tb, 0, stream>>>(logit_w, logT, DD, VV);

  const int M = BB * TT;
  embed_k<<<M, 256, 0, stream>>>(x, emb, h);

  for (int l = 0; l < LL; l++) {
    ln_rows<<<M, 256, 0, stream>>>(h, ln1_g + l * DD, ln1_b + l * DD, ybf);
    // qkv = y @ wqkv
    G<0>(ybf, DD, 0, 0, wqkvT + (size_t)l * 3 * DD * DD, DD, 0, 0,
         qkvbf, 3 * DD, 0, 0, nullptr, nullptr, 0, M, 3 * DD, DD, 1, stream);
    // S = Q @ K^T  (split-K x4, atomic accumulate into zeroed Smat)
    hipMemsetAsync(Smat, 0, (size_t)BB * HH * 256 * 256 * 4, stream);
    G<5>(qkvbf, HH * 3 * DD, (long)TT * 3 * DD, 3 * DD,
         qkvbf + DD, HH * 3 * DD, (long)TT * 3 * DD, 3 * DD,
         Smat, 256, (long)HH * 256 * 256, 256 * 256,
         nullptr, nullptr, 0, 256, 256, DD / 4, 4 * BB * HH, stream);
    softmax256<<<BB * HH * 256, 256, 0, stream>>>(Smat, Pbf);
    vtrans<<<dim3(DD / 32, 256 / 32, BB * HH), tb, 0, stream>>>(qkvbf, Vt);
    // O = P @ V
    G<0>(Pbf, 256, (long)HH * 256 * 256, 256 * 256,
         Vt, 256, (long)HH * DD * 256, (long)DD * 256,
         Obf, HH * DD, (long)TT * DD, DD,
         nullptr, nullptr, 0, 256, DD, 256, BB * HH, stream);
    // h += O @ wout + b
    G<2>(Obf, DD, 0, 0, woutT + (size_t)l * DD * DD, DD, 0, 0,
         h, DD, 0, 0, wout_b + l * DD, h, DD, M, DD, DD, 1, stream);
    ln_rows<<<M, 256, 0, stream>>>(h, ln2_g + l * DD, ln2_b + l * DD, ybf);
    // mid = lrelu(y @ ff1 + b1)
    G<3>(ybf, DD, 0, 0, ff1T + (size_t)l * 4 * DD * DD, DD, 0, 0,
         midbf, 4 * DD, 0, 0, ff1_b + (size_t)l * 4 * DD, nullptr, 0, M, 4 * DD, DD, 1, stream);
    // h += mid @ ff2 + b2
    G<2>(midbf, 4 * DD, 0, 0, ff2T + (size_t)l * DD * 4 * DD, 4 * DD, 0, 0,
         h, DD, 0, 0, ff2_b + l * DD, h, DD, M, DD, 4 * DD, 1, stream);
  }

  f2bf<<<(M * DD / 8) / 256, 256, 0, stream>>>(h, ybf);
  // logits = h @ logit_w + logit_b
  G<4>(ybf, DD, 0, 0, logT, DD, 0, 0,
       out, VV, 0, 0, logit_b, nullptr, 0, M, VV, DD, 1, stream);
}

// Round 6
// 1457.498 us; speedup vs baseline: 1.2324x; 1.0555x over previous
//
#include <hip/hip_runtime.h>

#define DD 1024
#define LL 4
#define HH 8
#define BB 2
#define TT 2048
#define VV 32000
#define SCALE_QK 0.08838834764831845f

typedef __bf16 bf16x8 __attribute__((ext_vector_type(8)));
typedef __bf16 bf16x4 __attribute__((ext_vector_type(4)));
typedef float  f32x4  __attribute__((ext_vector_type(4)));

__device__ __forceinline__ void gload_lds16(const void* g, void* l) {
  __builtin_amdgcn_global_load_lds((const __attribute__((address_space(1))) void*)g,
                                   (__attribute__((address_space(3))) void*)l, 16, 0, 0);
}

// =====================================================================
// 256x256 8-phase GEMM, deep staggered vmcnt (m201 discipline).
// Ledger (per-thread loads, steady state): entry out = {u(2t+1):4, u(2t+2):4}
//  p0 +2, p1 +2 -> 12 ; W1 vmcnt(8) waits u(2t+1) [5 phases old] -> 8
//  p2 +2, p3 +2 -> 12 ; W2 vmcnt(8) waits u(2t+2) [5 phases old] -> 8  (invariant)
// Tails: t=NT-1: W1 vmcnt(0), W2 skip. t=NT-2: W2 vmcnt(4).
// W1/W2 placed BEFORE the trailing barrier -> cross-wave LDS visibility.
// MODE 0: bf16 ; MODE 3: bf16 lrelu(acc+bias) ; MODE 4: f32 acc+bias
// =====================================================================
template<int MODE>
__global__ __launch_bounds__(512, 2)
void gemm256(const __bf16* __restrict__ A, long ldA,
             const __bf16* __restrict__ Bt, long ldB,
             void* __restrict__ Cv, long ldC,
             const float* __restrict__ bias,
             int K, int nby)
{
  extern __shared__ __attribute__((aligned(16))) char smem[];

  const int nwg = gridDim.x;
  const int o = blockIdx.x;
  const int q8 = nwg >> 3, r8 = nwg & 7;
  const int xcd = o & 7, idx = o >> 3;
  const int swz = (xcd < r8 ? xcd * (q8 + 1) : r8 * (q8 + 1) + (xcd - r8) * q8) + idx;
  const int bx = swz / nby, by = swz - bx * nby;
  const int m0 = by * 256, n0 = bx * 256;

  const int tid = threadIdx.x;
  const int wv = tid >> 6, ln = tid & 63;
  const int wm = wv >> 2, wn = wv & 3;

  const int u = (ln & 7) ^ (ln >> 3);
  const int dR = u >> 2;
  const int dK = (u & 3) << 3;
  const int row0 = (wv * 16 + (ln >> 3)) * 2 + dR;
  const __bf16* aS0 = A  + (size_t)(m0 + row0) * ldA + dK;
  const __bf16* aS1 = A  + (size_t)(m0 + row0 + 16) * ldA + dK;
  const __bf16* bS0 = Bt + (size_t)(n0 + row0) * ldB + dK;
  const __bf16* bS1 = Bt + (size_t)(n0 + row0 + 16) * ldB + dK;
  char* const dBase = smem + wv * 2048 + ln * 16;

  const int lr = ln & 15;
  const int gfr = ((((ln & 1) << 2) | ((ln >> 4) & 3)) ^ ((ln >> 1) & 7)) << 4;
  const int aRd = (wm * 64 + (lr >> 1)) * 128 + gfr;
  const int bRd = 65536 + (wn * 32 + (lr >> 1)) * 128 + gfr;

  f32x4 acc[8][4] = {};
  bf16x8 b[4];
  const int NT = K >> 6;

#define STG_A(tt, ks) { const int sl = ((2*(tt)+(ks)) & 3) * 16384; \
    gload_lds16(aS0 + (tt)*64 + (ks)*32, dBase + sl); \
    gload_lds16(aS1 + (tt)*64 + (ks)*32, dBase + sl + 1024); }
#define STG_B(tt, ks) { const int sl = ((2*(tt)+(ks)) & 3) * 16384 + 65536; \
    gload_lds16(bS0 + (tt)*64 + (ks)*32, dBase + sl); \
    gload_lds16(bS1 + (tt)*64 + (ks)*32, dBase + sl + 1024); }
#define BAR() __builtin_amdgcn_s_barrier()
#define PREMFMA() { asm volatile("s_waitcnt lgkmcnt(0)" ::: "memory"); __builtin_amdgcn_sched_barrier(0); }
#define MFMA_Q(MH) \
    __builtin_amdgcn_s_setprio(1); \
    _Pragma("unroll") \
    for (int i = 0; i < 4; i++) \
      _Pragma("unroll") \
      for (int j = 0; j < 4; j++) \
        acc[(MH)*4+i][j] = __builtin_amdgcn_mfma_f32_16x16x32_bf16(a[i], b[j], acc[(MH)*4+i][j], 0,0,0); \
    __builtin_amdgcn_s_setprio(0);

  // prologue: units 0,1 (tile0) + unit 2 (tile1,k0) = 12 loads; wait unit0 only.
  STG_A(0, 0); STG_B(0, 0); STG_A(0, 1); STG_B(0, 1);
  if (NT > 1) {
    STG_A(1, 0); STG_B(1, 0);
    asm volatile("s_waitcnt vmcnt(8)" ::: "memory");
  } else {
    asm volatile("s_waitcnt vmcnt(0)" ::: "memory");
  }
  BAR();

  for (int t = 0; t < NT; ++t) {
    const char* uA0 = smem + ((2 * t) & 3) * 16384;
    const char* uA1 = smem + ((2 * t + 1) & 3) * 16384;
    bf16x8 a[4];
    // ---- p0: m-half0, ksub0 ----
#pragma unroll
    for (int i = 0; i < 4; i++) a[i] = *(const bf16x8*)(uA0 + aRd + i * 1024);
#pragma unroll
    for (int j = 0; j < 4; j++) b[j] = *(const bf16x8*)(uA0 + bRd + j * 1024);
    if (t + 1 < NT) STG_A(t + 1, 1);
    BAR();
    PREMFMA();
    MFMA_Q(0);
    BAR();
    // ---- p1: m-half1, ksub0 ----
#pragma unroll
    for (int i = 0; i < 4; i++) a[i] = *(const bf16x8*)(uA0 + aRd + (4 + i) * 1024);
    if (t + 1 < NT) STG_B(t + 1, 1);
    BAR();
    PREMFMA();
    MFMA_Q(1);
    // W1: ensure unit 2t+1 (read by p2/p3) landed; staged 5 phases ago.
    if (t + 1 < NT) { asm volatile("s_waitcnt vmcnt(8)" ::: "memory"); }
    else            { asm volatile("s_waitcnt vmcnt(0)" ::: "memory"); }
    BAR();
    // ---- p2: m-half0, ksub1 ----
#pragma unroll
    for (int i = 0; i < 4; i++) a[i] = *(const bf16x8*)(uA1 + aRd + i * 1024);
#pragma unroll
    for (int j = 0; j < 4; j++) b[j] = *(const bf16x8*)(uA1 + bRd + j * 1024);
    if (t + 2 < NT) STG_A(t + 2, 0);
    BAR();
    PREMFMA();
    MFMA_Q(0);
    BAR();
    // ---- p3: m-half1, ksub1 ----
#pragma unroll
    for (int i = 0; i < 4; i++) a[i] = *(const bf16x8*)(uA1 + aRd + (4 + i) * 1024);
    if (t + 2 < NT) STG_B(t + 2, 0);
    BAR();
    PREMFMA();
    MFMA_Q(1);
    // W2: ensure unit 2t+2 (read by next p0/p1) landed; staged 5 phases ago.
    if (t + 2 < NT)      { asm volatile("s_waitcnt vmcnt(8)" ::: "memory"); }
    else if (t + 1 < NT) { asm volatile("s_waitcnt vmcnt(4)" ::: "memory"); }
    BAR();
  }
#undef STG_A
#undef STG_B
#undef BAR
#undef PREMFMA
#undef MFMA_Q

  const int rb = m0 + wm * 128 + (ln >> 4) * 4;
  const int cb = n0 + wn * 64 + (ln & 15);
#pragma unroll
  for (int i = 0; i < 8; i++)
#pragma unroll
    for (int j = 0; j < 4; j++) {
      const int col = cb + j * 16;
#pragma unroll
      for (int r = 0; r < 4; r++) {
        const int row = rb + i * 16 + r;
        float v = acc[i][j][r];
        const size_t ci = (size_t)row * ldC + col;
        if (MODE == 0)      ((__bf16*)Cv)[ci] = (__bf16)v;
        else if (MODE == 3) { v += bias[col]; ((__bf16*)Cv)[ci] = (__bf16)(v >= 0.f ? v : 0.01f * v); }
        else if (MODE == 4) ((float*)Cv)[ci] = v + bias[col];
      }
    }
}

// =====================================================================
// ring3 counted-vmcnt 128x128 NT GEMM (unchanged control from round 5)
// MODE 0: bf16 ; 1: f32 ; 2: f32 acc+bias+res ; 3: bf16 lrelu(acc+bias) ;
// MODE 4: f32 acc+bias ; 5: f32 atomicAdd (split-K, z=(kc<<4)|bh)
// =====================================================================
template<int MODE>
__global__ __launch_bounds__(256, 3)
void gemm_rt(const __bf16* __restrict__ A, long ldA, long aSB, long aSH,
             const __bf16* __restrict__ Bt, long ldB, long bSB, long bSH,
             void* __restrict__ Cv, long ldC, long cSB, long cSH,
             const float* __restrict__ bias,
             const float* __restrict__ res, long ldR,
             int K)
{
  int zbh = blockIdx.z;
  if (MODE == 5) {
    const int kc = zbh >> 4;
    zbh &= 15;
    A  += (size_t)kc * K;
    Bt += (size_t)kc * K;
  }
  const int zb = zbh >> 3, zh = zbh & 7;
  A  += (size_t)zb * aSB + (size_t)zh * aSH;
  Bt += (size_t)zb * bSB + (size_t)zh * bSH;
  const size_t cOff = (size_t)zb * cSB + (size_t)zh * cSH;

  const int nbx = gridDim.x, nby = gridDim.y;
  const int nwg = nbx * nby;
  const int fid = blockIdx.y * nbx + blockIdx.x;
  const int q8 = nwg >> 3, r8 = nwg & 7;
  const int xcd = fid & 7, idx = fid >> 3;
  const int swz = (xcd < r8 ? xcd * (q8 + 1) : r8 * (q8 + 1) + (xcd - r8) * q8) + idx;
  const int bx = swz / nby, by = swz - bx * nby;
  const int m0 = by * 128, n0 = bx * 128;

  __shared__ __attribute__((aligned(16))) char smem[49152];

  const int tid = threadIdx.x;
  const int wv = tid >> 6, ln = tid & 63;
  const int wm = wv >> 1, wn = wv & 1;

  const int ls = tid >> 3;
  const int gs = tid & 7;
  const int us = gs ^ (ls & 7);
  const int rs = 2 * ls + (us >> 2);
  const int ks = (us & 3) * 8;
  const __bf16* pA0 = A  + (size_t)(m0 + rs) * ldA + ks;
  const __bf16* pA1 = A  + (size_t)(m0 + 64 + rs) * ldA + ks;
  const __bf16* pB0 = Bt + (size_t)(n0 + rs) * ldB + ks;
  const __bf16* pB1 = Bt + (size_t)(n0 + 64 + rs) * ldB + ks;

  const int lr = ln & 15;
  const int gfr = ((((ln & 1) << 2) | ((ln >> 4) & 3)) ^ ((ln >> 1) & 7)) << 4;
  const int aR = (wm * 32 + (lr >> 1)) * 128 + gfr;
  const int bR = 24576 + (wn * 32 + (lr >> 1)) * 128 + gfr;

  f32x4 acc[4][4] = {};
  const int NT = K >> 5;

#define STG(sl) { \
    char* da = smem + (sl) * 8192 + tid * 16; \
    gload_lds16(pA0, da); gload_lds16(pA1, da + 4096); \
    char* db = da + 24576; \
    gload_lds16(pB0, db); gload_lds16(pB1, db + 4096); \
    pA0 += 32; pA1 += 32; pB0 += 32; pB1 += 32; }

  STG(0);
  if (NT > 1) {
    STG(1);
    asm volatile("s_waitcnt vmcnt(4)" ::: "memory");
  } else {
    asm volatile("s_waitcnt vmcnt(0)" ::: "memory");
  }
  __builtin_amdgcn_s_barrier();

  int sc = 0, sn = 1, sf = 2;
  for (int t = 0; t < NT; ++t) {
    if (t + 2 < NT) STG(sf);
    const char* ba = smem + sc * 8192;
    bf16x8 a[4], b[4];
#pragma unroll
    for (int i = 0; i < 4; i++) a[i] = *(const bf16x8*)(ba + aR + i * 1024);
#pragma unroll
    for (int j = 0; j < 4; j++) b[j] = *(const bf16x8*)(ba + bR + j * 1024);
    __builtin_amdgcn_s_setprio(1);
#pragma unroll
    for (int i = 0; i < 4; i++)
#pragma unroll
      for (int j = 0; j < 4; j++)
        acc[i][j] = __builtin_amdgcn_mfma_f32_16x16x32_bf16(a[i], b[j], acc[i][j], 0, 0, 0);
    __builtin_amdgcn_s_setprio(0);
    if (t + 1 < NT) {
      if (t + 2 < NT) { asm volatile("s_waitcnt vmcnt(4)" ::: "memory"); }
      else            { asm volatile("s_waitcnt vmcnt(0)" ::: "memory"); }
      __builtin_amdgcn_sched_barrier(0);
      __builtin_amdgcn_s_barrier();
    }
    const int tmp = sc; sc = sn; sn = sf; sf = tmp;
  }
#undef STG

  const int rb = m0 + wm * 64 + (ln >> 4) * 4;
  const int cb = n0 + wn * 64 + (ln & 15);
#pragma unroll
  for (int i = 0; i < 4; i++)
#pragma unroll
    for (int j = 0; j < 4; j++) {
      const int col = cb + j * 16;
#pragma unroll
      for (int r = 0; r < 4; r++) {
        const int row = rb + i * 16 + r;
        float v = acc[i][j][r];
        const size_t ci = cOff + (size_t)row * ldC + col;
        if (MODE == 0)      ((__bf16*)Cv)[ci] = (__bf16)v;
        else if (MODE == 1) ((float*)Cv)[ci] = v;
        else if (MODE == 2) ((float*)Cv)[ci] = v + bias[col] + res[(size_t)row * ldR + col];
        else if (MODE == 3) { v += bias[col]; ((__bf16*)Cv)[ci] = (__bf16)(v >= 0.f ? v : 0.01f * v); }
        else if (MODE == 4) ((float*)Cv)[ci] = v + bias[col];
        else if (MODE == 5) atomicAdd(&((float*)Cv)[ci], v);
      }
    }
}

// ---------------- weight transpose + fp32->bf16 ----------------
__global__ void wtrans(const float* __restrict__ W, __bf16* __restrict__ Wt, int K, int N)
{
  const size_t zo = (size_t)blockIdx.z * K * N;
  __shared__ float t[32][33];
  const int n0 = blockIdx.x * 32, k0 = blockIdx.y * 32;
  const int tx = threadIdx.x, ty = threadIdx.y;
#pragma unroll
  for (int r = 0; r < 4; r++)
    t[ty + r * 8][tx] = W[zo + (size_t)(k0 + ty + r * 8) * N + n0 + tx];
  __syncthreads();
#pragma unroll
  for (int r = 0; r < 4; r++)
    Wt[zo + (size_t)(n0 + ty + r * 8) * K + k0 + tx] = (__bf16)t[tx][ty + r * 8];
}

// ---------------- V transpose per (b,h) ----------------
__global__ void vtrans(const __bf16* __restrict__ qkv, __bf16* __restrict__ Vt)
{
  const int z = blockIdx.z, bb = z >> 3, hh = z & 7;
  const __bf16* src = qkv + ((size_t)bb * TT + hh) * (3 * DD) + 2 * DD;
  __bf16* dst = Vt + (size_t)z * DD * 256;
  __shared__ __bf16 t[32][33];
  const int n0 = blockIdx.x * 32, i0 = blockIdx.y * 32;
  const int tx = threadIdx.x, ty = threadIdx.y;
#pragma unroll
  for (int r = 0; r < 4; r++)
    t[ty + r * 8][tx] = src[(size_t)(i0 + ty + r * 8) * (HH * 3 * DD) + n0 + tx];
  __syncthreads();
#pragma unroll
  for (int r = 0; r < 4; r++)
    dst[(size_t)(n0 + ty + r * 8) * 256 + i0 + tx] = t[tx][ty + r * 8];
}

// ---------------- embedding gather ----------------
__global__ void embed_k(const int* __restrict__ x, const float* __restrict__ emb, float* __restrict__ h)
{
  const int row = blockIdx.x;
  const int tok = x[row];
  ((float4*)(h + (size_t)row * DD))[threadIdx.x] = ((const float4*)(emb + (size_t)tok * DD))[threadIdx.x];
}

// ---------------- layernorm row -> bf16 ----------------
__global__ void ln_rows(const float* __restrict__ x, const float* __restrict__ g,
                        const float* __restrict__ b, __bf16* __restrict__ y)
{
  const int row = blockIdx.x, t = threadIdx.x;
  const int wv = t >> 6, ln = t & 63;
  const float4 v = ((const float4*)(x + (size_t)row * DD))[t];
  float s  = v.x + v.y + v.z + v.w;
  float ss = v.x * v.x + v.y * v.y + v.z * v.z + v.w * v.w;
#pragma unroll
  for (int o = 32; o; o >>= 1) { s += __shfl_xor(s, o); ss += __shfl_xor(ss, o); }
  __shared__ float rs_[4], rss_[4];
  if (!ln) { rs_[wv] = s; rss_[wv] = ss; }
  __syncthreads();
  s  = rs_[0] + rs_[1] + rs_[2] + rs_[3];
  ss = rss_[0] + rss_[1] + rss_[2] + rss_[3];
  const float mu  = s * (1.0f / DD);
  const float var = ss * (1.0f / DD) - mu * mu;
  const float r   = rsqrtf(var + 1e-5f);
  const float4 gv = ((const float4*)g)[t];
  const float4 bv = ((const float4*)b)[t];
  bf16x4 o = { (__bf16)((v.x - mu) * r * gv.x + bv.x),
               (__bf16)((v.y - mu) * r * gv.y + bv.y),
               (__bf16)((v.z - mu) * r * gv.z + bv.z),
               (__bf16)((v.w - mu) * r * gv.w + bv.w) };
  ((bf16x4*)(y + (size_t)row * DD))[t] = o;
}

// ---------------- softmax over 256-wide rows -> bf16 ----------------
__global__ void softmax256(const float* __restrict__ S, __bf16* __restrict__ P)
{
  const int row = blockIdx.x, t = threadIdx.x;
  const int wv = t >> 6, ln = t & 63;
  const float v = S[(size_t)row * 256 + t] * SCALE_QK;
  float m = v;
#pragma unroll
  for (int o = 32; o; o >>= 1) m = fmaxf(m, __shfl_xor(m, o));
  __shared__ float red[8];
  if (!ln) red[wv] = m;
  __syncthreads();
  m = fmaxf(fmaxf(red[0], red[1]), fmaxf(red[2], red[3]));
  const float e = __expf(v - m);
  float s = e;
#pragma unroll
  for (int o = 32; o; o >>= 1) s += __shfl_xor(s, o);
  if (!ln) red[4 + wv] = s;
  __syncthreads();
  s = red[4] + red[5] + red[6] + red[7];
  P[(size_t)row * 256 + t] = (__bf16)(e / s);
}

// ---------------- fp32 -> bf16 convert ----------------
__global__ void f2bf(const float* __restrict__ h, __bf16* __restrict__ y)
{
  const size_t i = (size_t)blockIdx.x * 256 + threadIdx.x;
  const float4 a = ((const float4*)h)[2 * i];
  const float4 b = ((const float4*)h)[2 * i + 1];
  bf16x8 o = { (__bf16)a.x, (__bf16)a.y, (__bf16)a.z, (__bf16)a.w,
               (__bf16)b.x, (__bf16)b.y, (__bf16)b.z, (__bf16)b.w };
  ((bf16x8*)y)[i] = o;
}

template<int MODE>
static void G(const __bf16* A, long ldA, long aSB, long aSH,
              const __bf16* Bt, long ldB, long bSB, long bSH,
              void* C, long ldC, long cSB, long cSH,
              const float* bias, const float* res, long ldR,
              int M, int N, int K, int Z, hipStream_t s)
{
  gemm_rt<MODE><<<dim3(N / 128, M / 128, Z), 256, 0, s>>>(
      A, ldA, aSB, aSH, Bt, ldB, bSB, bSH, C, ldC, cSB, cSH, bias, res, ldR, K);
}

template<int MODE>
static void G256(const __bf16* A, long ldA, const __bf16* Bt, long ldB,
                 void* C, long ldC, const float* bias,
                 int M, int N, int K, hipStream_t s)
{
  hipFuncSetAttribute((const void*)gemm256<MODE>,
                      hipFuncAttributeMaxDynamicSharedMemorySize, 131072);
  const int nby = M / 256, nbx = N / 256;
  gemm256<MODE><<<dim3(nbx * nby), 512, 131072, s>>>(A, ldA, Bt, ldB, C, ldC, bias, K, nby);
}

extern "C" void kernel_launch(void* const* d_in, const int* in_sizes, int n_in,
                              void* d_out, int out_size, void* d_ws, size_t ws_size,
                              hipStream_t stream)
{
  const int*   x       = (const int*)  d_in[0];
  const float* emb     = (const float*)d_in[1];
  const float* ln1_g   = (const float*)d_in[2];
  const float* ln1_b   = (const float*)d_in[3];
  const float* wqkv    = (const float*)d_in[4];
  const float* wout_w  = (const float*)d_in[5];
  const float* wout_b  = (const float*)d_in[6];
  const float* ln2_g   = (const float*)d_in[7];
  const float* ln2_b   = (const float*)d_in[8];
  const float* ff1_w   = (const float*)d_in[9];
  const float* ff1_b   = (const float*)d_in[10];
  const float* ff2_w   = (const float*)d_in[11];
  const float* ff2_b   = (const float*)d_in[12];
  const float* logit_w = (const float*)d_in[13];
  const float* logit_b = (const float*)d_in[14];
  float* out = (float*)d_out;

  char* w = (char*)d_ws;
  size_t off = 0;
  auto take = [&](size_t bytes) { void* p = w + off; off += (bytes + 255) & ~(size_t)255; return p; };
  __bf16* wqkvT = (__bf16*)take((size_t)LL * 3 * DD * DD * 2);
  __bf16* woutT = (__bf16*)take((size_t)LL * DD * DD * 2);
  __bf16* ff1T  = (__bf16*)take((size_t)LL * 4 * DD * DD * 2);
  __bf16* ff2T  = (__bf16*)take((size_t)LL * DD * 4 * DD * 2);
  __bf16* logT  = (__bf16*)take((size_t)VV * DD * 2);
  float*  h     = (float*) take((size_t)BB * TT * DD * 4);
  __bf16* ybf   = (__bf16*)take((size_t)BB * TT * DD * 2);
  __bf16* qkvbf = (__bf16*)take((size_t)BB * TT * 3 * DD * 2);
  float*  Smat  = (float*) take((size_t)BB * HH * 256 * 256 * 4);
  __bf16* Pbf   = (__bf16*)take((size_t)BB * HH * 256 * 256 * 2);
  __bf16* Vt    = (__bf16*)take((size_t)BB * HH * DD * 256 * 2);
  __bf16* Obf   = (__bf16*)take((size_t)BB * TT * DD * 2);
  __bf16* midbf = (__bf16*)take((size_t)BB * TT * 4 * DD * 2);
  if (ws_size < off) return;

  const dim3 tb(32, 8);
  wtrans<<<dim3(3 * DD / 32, DD / 32, LL), tb, 0, stream>>>(wqkv,   wqkvT, DD, 3 * DD);
  wtrans<<<dim3(DD / 32,     DD / 32, LL), tb, 0, stream>>>(wout_w, woutT, DD, DD);
  wtrans<<<dim3(4 * DD / 32, DD / 32, LL), tb, 0, stream>>>(ff1_w,  ff1T,  DD, 4 * DD);
  wtrans<<<dim3(DD / 32, 4 * DD / 32, LL), tb, 0, stream>>>(ff2_w,  ff2T,  4 * DD, DD);
  wtrans<<<dim3(VV / 32,     DD / 32, 1),  tb, 0, stream>>>(logit_w, logT, DD, VV);

  const int M = BB * TT;
  embed_k<<<M, 256, 0, stream>>>(x, emb, h);

  for (int l = 0; l < LL; l++) {
    ln_rows<<<M, 256, 0, stream>>>(h, ln1_g + l * DD, ln1_b + l * DD, ybf);
    // qkv = y @ wqkv
    G<0>(ybf, DD, 0, 0, wqkvT + (size_t)l * 3 * DD * DD, DD, 0, 0,
         qkvbf, 3 * DD, 0, 0, nullptr, nullptr, 0, M, 3 * DD, DD, 1, stream);
    // S = Q @ K^T  (split-K x4, atomic accumulate into zeroed Smat)
    hipMemsetAsync(Smat, 0, (size_t)BB * HH * 256 * 256 * 4, stream);
    G<5>(qkvbf, HH * 3 * DD, (long)TT * 3 * DD, 3 * DD,
         qkvbf + DD, HH * 3 * DD, (long)TT * 3 * DD, 3 * DD,
         Smat, 256, (long)HH * 256 * 256, 256 * 256,
         nullptr, nullptr, 0, 256, 256, DD / 4, 4 * BB * HH, stream);
    softmax256<<<BB * HH * 256, 256, 0, stream>>>(Smat, Pbf);
    vtrans<<<dim3(DD / 32, 256 / 32, BB * HH), tb, 0, stream>>>(qkvbf, Vt);
    // O = P @ V
    G<0>(Pbf, 256, (long)HH * 256 * 256, 256 * 256,
         Vt, 256, (long)HH * DD * 256, (long)DD * 256,
         Obf, HH * DD, (long)TT * DD, DD,
         nullptr, nullptr, 0, 256, DD, 256, BB * HH, stream);
    // h += O @ wout + b
    G<2>(Obf, DD, 0, 0, woutT + (size_t)l * DD * DD, DD, 0, 0,
         h, DD, 0, 0, wout_b + l * DD, h, DD, M, DD, DD, 1, stream);
    ln_rows<<<M, 256, 0, stream>>>(h, ln2_g + l * DD, ln2_b + l * DD, ybf);
    // mid = lrelu(y @ ff1 + b1)
    G<3>(ybf, DD, 0, 0, ff1T + (size_t)l * 4 * DD * DD, DD, 0, 0,
         midbf, 4 * DD, 0, 0, ff1_b + (size_t)l * 4 * DD, nullptr, 0, M, 4 * DD, DD, 1, stream);
    // h += mid @ ff2 + b2
    G<2>(midbf, 4 * DD, 0, 0, ff2T + (size_t)l * DD * 4 * DD, 4 * DD, 0, 0,
         h, DD, 0, 0, ff2_b + l * DD, h, DD, M, DD, 4 * DD, 1, stream);
  }

  f2bf<<<(M * DD / 8) / 256, 256, 0, stream>>>(h, ybf);
  // logits = h @ logit_w + logit_b  (256^2 deep-vmcnt kernel)
  G256<4>(ybf, DD, logT, DD, out, VV, logit_b, M, VV, DD, stream);
}